// Round 10
// baseline (278.052 us; speedup 1.0000x reference)
//
#include <hip/hip_runtime.h>
#include <hip/hip_bf16.h>

typedef __bf16 bf16;
typedef __bf16 bf16x4 __attribute__((ext_vector_type(4)));
typedef __bf16 bf16x8 __attribute__((ext_vector_type(8)));
typedef float f32x4 __attribute__((ext_vector_type(4)));

#define MFMA16(a, b, c) __builtin_amdgcn_mfma_f32_16x16x32_bf16((a), (b), (c), 0, 0, 0)

// Problem constants
#define BB 2
#define HH 16
#define NN 2048
#define CC 1024
#define HD 64
#define NW (NN / 64)   // 64-key words per row = 32

// Q pre-scale: HD^-0.5 * log2(e), so attention can use exp2 directly.
#define QSCALE 0.1803368867f

// ---------------------------------------------------------------------------
// Per-block dtype detectors (512-word scan, L2-hot, wave-uniform result).
// ---------------------------------------------------------------------------
__device__ __forceinline__ int detect_f32_block(const unsigned int* __restrict__ w) {
    __shared__ int bfc_s, tot_s;
    if (threadIdx.x == 0) { bfc_s = 0; tot_s = 0; }
    __syncthreads();
    int bfc = 0, tot = 0;
    for (int i = threadIdx.x; i < 512; i += blockDim.x) {
        unsigned v = w[i];
        if (v != 0u) {
            tot++;
            unsigned e = (v >> 7) & 0xFFu;
            if (e >= 100u && e <= 140u) bfc++;
        }
    }
    atomicAdd(&bfc_s, bfc); atomicAdd(&tot_s, tot);
    __syncthreads();
    int r = (2 * bfc_s < tot_s) ? 1 : 0;
    __syncthreads();
    return r;
}

// mask element size: int64 -> 8, int32/fp32 -> 4, int16/bf16 -> 2, byte -> 1
__device__ __forceinline__ int detect_esz_block(const unsigned int* __restrict__ w) {
    __shared__ int ok8s, ok4s, ok2s;
    if (threadIdx.x == 0) { ok8s = 1; ok4s = 1; ok2s = 1; }
    __syncthreads();
    int ok8 = 1, ok4 = 1, ok2 = 1;
    for (int i = threadIdx.x; i < 512; i += blockDim.x) {
        unsigned v = w[i];
        if ((i & 1) && v != 0u) ok8 = 0;
        if (!(v == 0u || v == 1u || v == 0x3F800000u)) ok4 = 0;
        unsigned lo = v & 0xFFFFu, hi = v >> 16;
        if (!((lo == 0u || lo == 1u || lo == 0x3F80u) &&
              (hi == 0u || hi == 1u || hi == 0x3F80u))) ok2 = 0;
    }
    if (!ok8) atomicAnd(&ok8s, 0);
    if (!ok4) atomicAnd(&ok4s, 0);
    if (!ok2) atomicAnd(&ok2s, 0);
    __syncthreads();
    int r = ok8s ? 8 : (ok4s ? 4 : (ok2s ? 2 : 1));
    __syncthreads();
    return r;
}

// 8-elem fp32->bf16 (or passthrough) convert
__device__ __forceinline__ void cvt8(const void* __restrict__ src, bf16* __restrict__ dst,
                                     size_t e, int f32) {
    bf16x8 v;
    if (f32) {
        const f32x4* S = (const f32x4*)((const float*)src + e);
        f32x4 a = S[0], b = S[1];
        v[0] = (bf16)a[0]; v[1] = (bf16)a[1]; v[2] = (bf16)a[2]; v[3] = (bf16)a[3];
        v[4] = (bf16)b[0]; v[5] = (bf16)b[1]; v[6] = (bf16)b[2]; v[7] = (bf16)b[3];
    } else {
        v = *(const bf16x8*)((const bf16*)src + e);
    }
    *(bf16x8*)&dst[e] = v;
}

// ---------------------------------------------------------------------------
// Kernel: standalone convert (used for Wp after attn frees its slot).
// ---------------------------------------------------------------------------
__global__ __launch_bounds__(256) void cvt_bf16_kernel(const void* __restrict__ src,
                                                       bf16* __restrict__ dst) {
    const int f32 = detect_f32_block((const unsigned int*)src);
    size_t e = ((size_t)blockIdx.x * 256 + threadIdx.x) * 8;
    cvt8(src, dst, e, f32);
}

// ---------------------------------------------------------------------------
// Fused prep kernel: [0,2048) mask->bitmask; [2048,3584) Wqkv cvt;
// [3584,5632) X cvt (tier A only — grid size selects).
// ---------------------------------------------------------------------------
__global__ __launch_bounds__(256) void prep_kernel(const void* __restrict__ maskp,
                                                   unsigned long long* __restrict__ bm,
                                                   const void* __restrict__ Wqkv,
                                                   bf16* __restrict__ W16,
                                                   const void* __restrict__ x,
                                                   bf16* __restrict__ X16) {
    const int bid = blockIdx.x;
    if (bid < 2048) {
        const int esz = detect_esz_block((const unsigned int*)maskp);  // wave-uniform
        const int lane = threadIdx.x & 63;
        const int wave = threadIdx.x >> 6;
        const long wbase = ((long)bid * 4 + wave) * 16;
        for (int i = 0; i < 16; i++) {
            long w = wbase + i;
            long idx = w * 64 + lane;
            bool mk;
            if (esz == 4)      mk = ((const unsigned int*)maskp)[idx] != 0u;
            else if (esz == 2) mk = ((const unsigned short*)maskp)[idx] != 0;
            else if (esz == 8) mk = ((const unsigned long long*)maskp)[idx] != 0ull;
            else               mk = ((const unsigned char*)maskp)[idx] != 0;
            unsigned long long b = __ballot(mk);
            if (lane == 0) bm[w] = b;
        }
    } else if (bid < 3584) {
        const int f32 = detect_f32_block((const unsigned int*)Wqkv);
        size_t e = ((size_t)(bid - 2048) * 256 + threadIdx.x) * 8;
        cvt8(Wqkv, W16, e, f32);
    } else {
        const int f32 = detect_f32_block((const unsigned int*)x);
        size_t e = ((size_t)(bid - 3584) * 256 + threadIdx.x) * 8;
        cvt8(x, X16, e, f32);
    }
}

// ---------------------------------------------------------------------------
// async 16B global -> LDS copy (direct-to-LDS, no VGPR round-trip).
// LDS dest must be wave-uniform base; HW adds lane*16.
// ---------------------------------------------------------------------------
__device__ __forceinline__ void async_cp16(const bf16* g, bf16* l) {
    __builtin_amdgcn_global_load_lds((const __attribute__((address_space(1))) void*)g,
                                     (__attribute__((address_space(3))) void*)l,
                                     16, 0, 0);
}

// ---------------------------------------------------------------------------
// Fast GEMM core v2 (T3-minimum): C[128x128] = A[128xK]*B[128xK]^T, K=1024.
// Single-barrier double-buffered K-loop: tile kt+1's global_load_lds are
// issued BEFORE computing tile kt; the iter-end __syncthreads (vmcnt-0
// drain) is the only sync. Load latency hides under 32 MFMAs. Same pattern
// race-validated in attn v10/v12. ldsA/ldsB are 2x(128x64) each (64KB tot).
// ---------------------------------------------------------------------------
template<int APERM>
__device__ __forceinline__ void gemm_tile_fast(const bf16* __restrict__ Ap,
                                               const bf16* __restrict__ Bp,
                                               int m0, int n0,
                                               bf16* ldsA, bf16* ldsB,
                                               f32x4 acc[4][4]) {
    const int K = 1024;
    const int tid = threadIdx.x, lane = tid & 63, wave = tid >> 6;
    const int l15 = lane & 15, q4 = lane >> 4;
    const int mw = (wave & 1) * 64, nw = (wave >> 1) * 64;

    #pragma unroll
    for (int i = 0; i < 4; i++)
        #pragma unroll
        for (int j = 0; j < 4; j++) {
            f32x4 z = {0.f, 0.f, 0.f, 0.f};
            acc[i][j] = z;
        }

    const int rA = tid >> 3;          // row within 32-row issue group
    const int colc = (tid & 7) << 3;  // col (elems) within 64-wide tile

    auto stage = [&](int kt, int buf) {
        #pragma unroll
        for (int i = 0; i < 4; i++) {
            int r = i * 32 + rA;
            size_t ae;
            if (APERM) {
                int m = m0 + r;
                ae = (((size_t)(m >> 11) * HH + kt) * NN + (m & (NN - 1))) * HD + colc;
            } else {
                ae = (size_t)(m0 + r) * K + kt * 64 + colc;
            }
            async_cp16(&Ap[ae], &ldsA[buf * 8192 + i * 2048 + wave * 512]);
            size_t be = (size_t)(n0 + r) * K + kt * 64 + colc;
            async_cp16(&Bp[be], &ldsB[buf * 8192 + i * 2048 + wave * 512]);
        }
    };

    stage(0, 0);
    __syncthreads();   // drain tile 0

    for (int kt = 0; kt < 16; ++kt) {
        // issue next tile's loads into the other buffer (readers of that
        // buffer finished before the barrier we just crossed)
        if (kt < 15) stage(kt + 1, (kt + 1) & 1);
        const bf16* lA = &ldsA[(kt & 1) * 8192];
        const bf16* lB = &ldsB[(kt & 1) * 8192];
        #pragma unroll
        for (int ks = 0; ks < 2; ks++) {
            bf16x8 af[4], bfr[4];
            #pragma unroll
            for (int i = 0; i < 4; i++)
                af[i] = *(const bf16x8*)&lA[(mw + i * 16 + l15) * 64 + ks * 32 + q4 * 8];
            #pragma unroll
            for (int j = 0; j < 4; j++)
                bfr[j] = *(const bf16x8*)&lB[(nw + j * 16 + l15) * 64 + ks * 32 + q4 * 8];
            #pragma unroll
            for (int i = 0; i < 4; i++)
                #pragma unroll
                for (int j = 0; j < 4; j++)
                    acc[i][j] = MFMA16(af[i], bfr[j], acc[i][j]);
        }
        __syncthreads();   // drains prefetch (vmcnt 0) + syncs buffer reuse
    }
}

// ---------------------------------------------------------------------------
// Legacy GEMM core (register-staged, in-loop fp32->bf16): tier-B qkv only.
// ---------------------------------------------------------------------------
__device__ __forceinline__ void gemm_tile(const void* __restrict__ Ap,
                                          const bf16* __restrict__ Bp,
                                          int K, int m0, int n0,
                                          int af32, int aperm,
                                          bf16* ldsA, bf16* ldsB,
                                          f32x4 acc[4][4]) {
    const int tid = threadIdx.x, lane = tid & 63, wave = tid >> 6;
    const int l15 = lane & 15, q4 = lane >> 4;
    const int mw = (wave & 1) * 64, nw = (wave >> 1) * 64;

    #pragma unroll
    for (int i = 0; i < 4; i++)
        #pragma unroll
        for (int j = 0; j < 4; j++) {
            f32x4 z = {0.f, 0.f, 0.f, 0.f};
            acc[i][j] = z;
        }

    const int nkt = K / 64;
    for (int kt = 0; kt < nkt; ++kt) {
        __syncthreads();
        #pragma unroll
        for (int c0 = 0; c0 < 4; c0++) {
            int c = tid + c0 * 256;               // 1024 chunks of 8 elems
            int r = c >> 3, kc = (c & 7) << 3;
            size_t ae;
            if (aperm) {
                int m = m0 + r;
                ae = (((size_t)(m >> 11) * HH + kt) * NN + (m & (NN - 1))) * HD + kc;
            } else {
                ae = (size_t)(m0 + r) * K + kt * 64 + kc;
            }
            bf16x8 av;
            if (af32) {
                const f32x4* Af = (const f32x4*)((const float*)Ap + ae);
                f32x4 a0 = Af[0], a1 = Af[1];
                av[0] = (bf16)a0[0]; av[1] = (bf16)a0[1]; av[2] = (bf16)a0[2]; av[3] = (bf16)a0[3];
                av[4] = (bf16)a1[0]; av[5] = (bf16)a1[1]; av[6] = (bf16)a1[2]; av[7] = (bf16)a1[3];
            } else {
                av = *(const bf16x8*)((const bf16*)Ap + ae);
            }
            *(bf16x8*)&ldsA[r * 72 + kc] = av;
            size_t be = (size_t)(n0 + r) * K + kt * 64 + kc;
            *(bf16x8*)&ldsB[r * 72 + kc] = *(const bf16x8*)&Bp[be];
        }
        __syncthreads();
        #pragma unroll
        for (int ks = 0; ks < 2; ks++) {
            bf16x8 af[4], bfr[4];
            #pragma unroll
            for (int i = 0; i < 4; i++)
                af[i] = *(bf16x8*)&ldsA[(mw + i * 16 + l15) * 72 + ks * 32 + q4 * 8];
            #pragma unroll
            for (int j = 0; j < 4; j++)
                bfr[j] = *(bf16x8*)&ldsB[(nw + j * 16 + l15) * 72 + ks * 32 + q4 * 8];
            #pragma unroll
            for (int i = 0; i < 4; i++)
                #pragma unroll
                for (int j = 0; j < 4; j++)
                    acc[i][j] = MFMA16(af[i], bfr[j], acc[i][j]);
        }
    }
}

// ---------------------------------------------------------------------------
// Shared QKV epilogue. 'which' is block-uniform (n0 multiple of 128).
// V blocks pack 4 consecutive-m values into one b64 store.
// ---------------------------------------------------------------------------
__device__ __forceinline__ void qkv_epilogue(f32x4 acc[4][4], int m0, int n0,
                                             bf16* __restrict__ Qb,
                                             bf16* __restrict__ Kb,
                                             bf16* __restrict__ Vt) {
    const int tid = threadIdx.x, lane = tid & 63, wave = tid >> 6;
    const int l15 = lane & 15, q4 = lane >> 4;
    const int mw = (wave & 1) * 64, nw = (wave >> 1) * 64;

    if (n0 >= 2 * CC) {
        // V region: packed bf16x4 stores along nq
        #pragma unroll
        for (int i = 0; i < 4; i++) {
            #pragma unroll
            for (int j = 0; j < 4; j++) {
                int n = n0 - 2 * CC + nw + j * 16 + l15;   // 0..1023
                int h = n >> 6, d = n & 63;
                int mbase = m0 + mw + i * 16 + q4 * 4;     // 4 consecutive m, no 2048-cross
                int b = mbase >> 11, nq = mbase & (NN - 1);
                bf16x4 pv;
                #pragma unroll
                for (int r = 0; r < 4; r++) pv[r] = (bf16)acc[i][j][r];
                *(bf16x4*)&Vt[((size_t)(b * HH + h) * HD + d) * NN + nq] = pv;
            }
        }
    } else {
        const int isK = n0 >= CC;
        #pragma unroll
        for (int i = 0; i < 4; i++) {
            #pragma unroll
            for (int j = 0; j < 4; j++) {
                #pragma unroll
                for (int r = 0; r < 4; r++) {
                    int m = m0 + mw + i * 16 + q4 * 4 + r;
                    int n = (n0 & (CC - 1)) + nw + j * 16 + l15;
                    int h = n >> 6, d = n & 63;
                    int b = m >> 11, nq = m & (NN - 1);
                    size_t bh = (size_t)(b * HH + h);
                    float v = acc[i][j][r];
                    if (isK) Kb[(bh * NN + nq) * HD + d] = (bf16)v;
                    else     Qb[(bh * NN + nq) * HD + d] = (bf16)(v * QSCALE);
                }
            }
        }
    }
}

// ---------------------------------------------------------------------------
// Kernel 1a: QKV projection, fast path (A pre-converted to bf16).
// ---------------------------------------------------------------------------
__global__ __launch_bounds__(256, 2) void qkv_fast_kernel(const bf16* __restrict__ X16,
                                                          const bf16* __restrict__ Wqkv,
                                                          bf16* __restrict__ Qb,
                                                          bf16* __restrict__ Kb,
                                                          bf16* __restrict__ Vt) {
    __shared__ alignas(16) bf16 ldsA[2 * 128 * 64];
    __shared__ alignas(16) bf16 ldsB[2 * 128 * 64];
    f32x4 acc[4][4];
    const int m0 = blockIdx.y * 128, n0 = blockIdx.x * 128;
    gemm_tile_fast<0>(X16, Wqkv, m0, n0, ldsA, ldsB, acc);
    qkv_epilogue(acc, m0, n0, Qb, Kb, Vt);
}

// ---------------------------------------------------------------------------
// Kernel 1b: QKV projection, legacy path (fp32/bf16 A, reg staging). Tier B.
// ---------------------------------------------------------------------------
__global__ __launch_bounds__(256, 2) void qkv_kernel(const void* __restrict__ X,
                                                     const bf16* __restrict__ Wqkv,
                                                     bf16* __restrict__ Qb,
                                                     bf16* __restrict__ Kb,
                                                     bf16* __restrict__ Vt) {
    __shared__ alignas(16) bf16 ldsA[128 * 72];
    __shared__ alignas(16) bf16 ldsB[128 * 72];
    const int f32 = detect_f32_block((const unsigned int*)X);
    f32x4 acc[4][4];
    const int m0 = blockIdx.y * 128, n0 = blockIdx.x * 128;
    gemm_tile(X, Wqkv, 1024, m0, n0, f32, 0, ldsA, ldsB, acc);
    qkv_epilogue(acc, m0, n0, Qb, Kb, Vt);
}

// ---------------------------------------------------------------------------
// Kernel 2: flash attention v12 (unchanged from R9 measurement).
// ---------------------------------------------------------------------------
__global__ __launch_bounds__(256, 2) void attn_kernel(const bf16* __restrict__ Qb,
                                                      const bf16* __restrict__ Kb,
                                                      const bf16* __restrict__ Vt,
                                                      const unsigned long long* __restrict__ bm,
                                                      bf16* __restrict__ Ob) {
    __shared__ alignas(16) bf16 Kt[2][64 * 64];
    __shared__ alignas(16) bf16 Vs[2][64 * 64];    // [d][key], swizzled chunks
    __shared__ alignas(16) bf16 Ps[4][32 * 72];    // per-wave P tile (swizzled)

    // XCD swizzle: 512 blocks; XCD x gets logical blocks [x*64, x*64+64) = 4 bh
    const int wg = blockIdx.y * (NN / 128) + blockIdx.x;   // 512 blocks
    const int swzb = (wg & 7) * 64 + (wg >> 3);            // bijective (512%8==0)
    const int bh = swzb >> 4;
    const int qb = (swzb & 15) * 128;
    const int b = bh >> 4;
    const int tid = threadIdx.x, lane = tid & 63, wave = tid >> 6;
    const int l15 = lane & 15, q4 = lane >> 4;

    const bf16* Qp = Qb + (size_t)bh * NN * HD;
    const bf16* Kp = Kb + (size_t)bh * NN * HD;
    const bf16* Vp = Vt + (size_t)bh * HD * NN;

    // staging geometry: chunk g = wave*64 + lane + s2*256; row = g>>3,
    // logical chunk fetched = (g&7)^(row&7) (XOR swizzle on global source).
    const int srow0 = (wave * 64 + lane) >> 3;
    const int sc0 = ((wave * 64 + lane) & 7) ^ (srow0 & 7);
    const int srow1 = (wave * 64 + lane + 256) >> 3;
    const int sc1 = ((wave * 64 + lane + 256) & 7) ^ (srow1 & 7);

    // Q fragments for both 16-row halves: rows qrb + h*16 + l15
    const int qrb = qb + wave * 32;
    bf16x8 qf[2][2];
    #pragma unroll
    for (int h = 0; h < 2; h++)
        #pragma unroll
        for (int s = 0; s < 2; s++)
            qf[h][s] = *(const bf16x8*)&Qp[(size_t)(qrb + h * 16 + l15) * HD + s * 32 + q4 * 8];

    // ones B-fragment for the denominator MFMA
    bf16x8 ones;
    #pragma unroll
    for (int i = 0; i < 8; i++) ones[i] = (bf16)1.0f;

    const f32x4 FZ = {0.f, 0.f, 0.f, 0.f};

    f32x4 o[2][4];
    f32x4 lacc[2] = {FZ, FZ};
    #pragma unroll
    for (int h = 0; h < 2; h++)
        #pragma unroll
        for (int jd = 0; jd < 4; jd++) o[h][jd] = FZ;

    // bitmask: this lane's q-row word (S^T: one q per lane, l15) per half
    const unsigned long long* bmr = bm + ((size_t)b * NN + qrb + l15) * NW;

    bf16* Pw = &Ps[wave][0];
    const int swzP = (l15 >> 1) & 7;          // P block swizzle for this q-row
    const int pwrow = l15 * 72;               // P row base (elems), half adds 16*72

    // swizzled LDS read chunk offsets (elems) for K/V fragment loads
    const int rc0 = ((0 * 4 + q4) ^ (l15 & 7)) * 8;   // ks=0
    const int rc1 = ((1 * 4 + q4) ^ (l15 & 7)) * 8;   // ks=1

    // ---- helper lambdas (all static indexing after inlining) ----
    auto QK = [&](const bf16* KtC, f32x4 (&sj)[2][4]) {
        #pragma unroll
        for (int j = 0; j < 4; j++) {
            bf16x8 kf0 = *(const bf16x8*)&KtC[(j * 16 + l15) * 64 + rc0];
            sj[0][j] = MFMA16(kf0, qf[0][0], FZ);
            sj[1][j] = MFMA16(kf0, qf[1][0], FZ);
            bf16x8 kf1 = *(const bf16x8*)&KtC[(j * 16 + l15) * 64 + rc1];
            sj[0][j] = MFMA16(kf1, qf[0][1], sj[0][j]);
            sj[1][j] = MFMA16(kf1, qf[1][1], sj[1][j]);
        }
    };
    auto EXPSTORE = [&](f32x4 (&sj)[2][4], unsigned (&s0)[2], unsigned (&s1)[2]) {
        #pragma unroll
        for (int h = 0; h < 2; h++) {
            #pragma unroll
            for (int j = 0; j < 4; j++) {
                unsigned w = (j < 2) ? s0[h] : s1[h];
                unsigned ws = (j & 1) ? (w >> 16) : w;
                bf16x4 pv;
                #pragma unroll
                for (int r = 0; r < 4; r++) {
                    unsigned bit = (ws >> r) & 1u;
                    float ex = __builtin_amdgcn_exp2f(sj[h][j][r]);
                    pv[r] = (bf16)(bit ? ex : 0.f);
                }
                const int blk = (2 * j + (q4 >> 1)) ^ swzP;
                *(bf16x4*)&Pw[(h * 16 * 72) + pwrow + blk * 8 + (q4 & 1) * 4] = pv;
            }
        }
    };
    auto PV = [&](const bf16* VsC) {
        __builtin_amdgcn_s_setprio(1);
        #pragma unroll
        for (int ks = 0; ks < 2; ks++) {
            const int psw = ((4 * ks + q4) ^ swzP) * 8;
            bf16x8 pf0 = *(bf16x8*)&Pw[pwrow + psw];
            bf16x8 pf1 = *(bf16x8*)&Pw[(16 * 72) + pwrow + psw];
            lacc[0] = MFMA16(pf0, ones, lacc[0]);
            lacc[1] = MFMA16(pf1, ones, lacc[1]);
            const int rcv = (ks ? rc1 : rc0);
            #pragma unroll
            for (int jd = 0; jd < 4; jd++) {
                bf16x8 vf = *(const bf16x8*)&VsC[(jd * 16 + l15) * 64 + rcv];
                o[0][jd] = MFMA16(pf0, vf, o[0][jd]);
                o[1][jd] = MFMA16(pf1, vf, o[1][jd]);
            }
        }
        __builtin_amdgcn_s_setprio(0);
    };

    // ---- prologue: stage tile 0 (K and V), mask(0); then K1 + QK(0)
    async_cp16(&Kp[(size_t)srow0 * HD + sc0 * 8], &Kt[0][(wave * 64) * 8]);
    async_cp16(&Kp[(size_t)srow1 * HD + sc1 * 8], &Kt[0][(wave * 64 + 256) * 8]);
    async_cp16(&Vp[(size_t)srow0 * NN + sc0 * 8], &Vs[0][(wave * 64) * 8]);
    async_cp16(&Vp[(size_t)srow1 * NN + sc1 * 8], &Vs[0][(wave * 64 + 256) * 8]);
    unsigned long long mwreg[2];
    #pragma unroll
    for (int h = 0; h < 2; h++) mwreg[h] = bmr[(size_t)h * 16 * NW];
    __syncthreads();   // drain tile-0 loads

    // prefetch K tile 1 (slot 1 untouched so far)
    async_cp16(&Kp[(size_t)(64 + srow0) * HD + sc0 * 8], &Kt[1][(wave * 64) * 8]);
    async_cp16(&Kp[(size_t)(64 + srow1) * HD + sc1 * 8], &Kt[1][(wave * 64 + 256) * 8]);

    f32x4 sjA[2][4], sjB[2][4];
    unsigned mA0[2], mA1[2], mB0[2], mB1[2];

    QK(&Kt[0][0], sjA);                         // S for tile 0
    #pragma unroll
    for (int h = 0; h < 2; h++) {
        mA0[h] = ((unsigned)mwreg[h]) >> (q4 * 4);
        mA1[h] = ((unsigned)(mwreg[h] >> 32)) >> (q4 * 4);
        mwreg[h] = bmr[(size_t)h * 16 * NW + 1];
    }
    __syncthreads();   // drain K tile-1 loads (all waves' QK(0) reads done)

    // ---- skewed steady-state: STEP(kt) = QK(kt) || finish(kt-1)
    // Slot usage inside STEP(kt):  K write (kt+1)&1 | K read kt&1
    //                              V write kt&1     | V read (kt-1)&1   (disjoint)
    auto STEP = [&](int kt, f32x4 (&sjP)[2][4], f32x4 (&sjC)[2][4],
                    unsigned (&s0P)[2], unsigned (&s1P)[2],
                    unsigned (&s0N)[2], unsigned (&s1N)[2]) {
        const int ktn = (kt + 1) & (NN / 64 - 1);   // kt=31 wraps (garbage ok)
        // 1. K prefetch for kt+1 (slot (kt+1)&1; last readers ran in STEP(kt-1))
        {
            bf16* KtN = &Kt[(kt + 1) & 1][0];
            async_cp16(&Kp[(size_t)(ktn * 64 + srow0) * HD + sc0 * 8], &KtN[(wave * 64) * 8]);
            async_cp16(&Kp[(size_t)(ktn * 64 + srow1) * HD + sc1 * 8], &KtN[(wave * 64 + 256) * 8]);
        }
        // 2. V prefetch for THIS tile kt (slot kt&1; consumed by PV(kt) next
        //    STEP after this step's barrier; prior content V[kt-2] done in
        //    STEP(kt-1) behind its barrier; disjoint from PV's read slot).
        {
            bf16* VsN = &Vs[kt & 1][0];
            async_cp16(&Vp[(size_t)srow0 * NN + kt * 64 + sc0 * 8], &VsN[(wave * 64) * 8]);
            async_cp16(&Vp[(size_t)srow1 * NN + kt * 64 + sc1 * 8], &VsN[(wave * 64 + 256) * 8]);
        }
        // 3. QK(kt): MFMAs issue; results not consumed until next STEP
        QK(&Kt[kt & 1][0], sjC);
        // 4+5. finish tile kt-1 in the MFMA shadow: exp/mask -> P -> PV
        EXPSTORE(sjP, s0P, s1P);
        PV(&Vs[(kt - 1) & 1][0]);
        // 6. mask shifts for tile kt (consumed next STEP); prefetch mask kt+1
        #pragma unroll
        for (int h = 0; h < 2; h++) {
            s0N[h] = ((unsigned)mwreg[h]) >> (q4 * 4);
            s1N[h] = ((unsigned)(mwreg[h] >> 32)) >> (q4 * 4);
            mwreg[h] = bmr[(size_t)h * 16 * NW + ktn];
        }
        // 7. single barrier: drains K/V prefetch, syncs buffer reuse
        __syncthreads();
    };

    for (int kt = 1; kt <= 29; kt += 2) {
        STEP(kt,     sjA, sjB, mA0, mA1, mB0, mB1);
        STEP(kt + 1, sjB, sjA, mB0, mB1, mA0, mA1);
    }
    STEP(31, sjA, sjB, mA0, mA1, mB0, mB1);

    // ---- tail: finish tile 31 (V[31] staged in slot 1, drained at STEP(31))
    EXPSTORE(sjB, mB0, mB1);
    PV(&Vs[1][0]);

    // normalize + write (lacc[h][r] = rowsum for row h*16+q4*4+r)
    #pragma unroll
    for (int h = 0; h < 2; h++) {
        float rl[4];
        #pragma unroll
        for (int r = 0; r < 4; r++) rl[r] = 1.0f / lacc[h][r];
        #pragma unroll
        for (int jd = 0; jd < 4; jd++) {
            #pragma unroll
            for (int r = 0; r < 4; r++) {
                int q = qrb + h * 16 + q4 * 4 + r;
                int d = jd * 16 + l15;
                Ob[((size_t)bh * NN + q) * HD + d] = (bf16)(o[h][jd][r] * rl[r]);
            }
        }
    }
}

// ---------------------------------------------------------------------------
// Kernel 3: output projection + bias, fast path (both tiers; A always bf16).
// ---------------------------------------------------------------------------
__global__ __launch_bounds__(256, 2) void proj_fast_kernel(const bf16* __restrict__ Ain,
                                                           const bf16* __restrict__ Wp16,
                                                           const void* __restrict__ biasp,
                                                           void* __restrict__ Outd,
                                                           void* __restrict__ Tmp,
                                                           int direct) {
    __shared__ alignas(16) bf16 ldsA[2 * 128 * 64];
    __shared__ alignas(16) bf16 ldsB[2 * 128 * 64];
    const int f32 = detect_f32_block((const unsigned int*)biasp);
    f32x4 acc[4][4];
    const int m0 = blockIdx.y * 128, n0 = blockIdx.x * 128;
    gemm_tile_fast<1>(Ain, Wp16, m0, n0, ldsA, ldsB, acc);

    const int tid = threadIdx.x, lane = tid & 63, wave = tid >> 6;
    const int l15 = lane & 15, q4 = lane >> 4;
    const int mw = (wave & 1) * 64, nw = (wave >> 1) * 64;
    #pragma unroll
    for (int i = 0; i < 4; i++) {
        #pragma unroll
        for (int j = 0; j < 4; j++) {
            #pragma unroll
            for (int r = 0; r < 4; r++) {
                int m = m0 + mw + i * 16 + q4 * 4 + r;
                int n = n0 + nw + j * 16 + l15;
                float bv = f32 ? ((const float*)biasp)[n] : (float)((const bf16*)biasp)[n];
                float val = acc[i][j][r] + bv;
                size_t idx = (size_t)m * CC + n;
                if (f32) {
                    if (direct || idx >= (size_t)2097152)   // byte off >= 8MB
                        ((float*)Outd)[idx] = val;
                    else
                        ((float*)Tmp)[idx] = val;
                } else {
                    if (direct) ((bf16*)Outd)[idx] = (bf16)val;
                    else        ((bf16*)Tmp)[idx] = (bf16)val;
                }
            }
        }
    }
}

// ---------------------------------------------------------------------------
// Memory map (fp32 output established => d_out = 16.78 MB):
//  d_out: [0, 8.39M)        Q scratch (tier B: attention O in-place)
//         [8.39M, 14.68M)   W_qkv bf16 (dead after qkv)
//         [14.68M, 15.73M)  key bitmask (dead after attn)
//  ws:    [0, 8.39M)        Kb (tier B: proj low-half staging after attn)
//         [8.39M, 16.78M)   Vt; after attn: Wp16 bf16 (2.1 MB) at 8.39M
//         tier A adds @16.78M: X16 bf16 (dead after qkv) then Ob (attn out)
// ---------------------------------------------------------------------------
extern "C" void kernel_launch(void* const* d_in, const int* in_sizes, int n_in,
                              void* d_out, int out_size, void* d_ws, size_t ws_size,
                              hipStream_t stream) {
    const void* x    = d_in[0];
    const void* mask = d_in[1];
    const void* Wqkv = d_in[2];
    const void* Wp   = d_in[3];
    const void* bias = d_in[4];

    char* ws = (char*)d_ws;
    const size_t QS  = (size_t)BB * HH * NN * HD;     // 4,194,304 elems
    const size_t QSB = QS * sizeof(bf16);             // 8,388,608 bytes
    bf16* Qb   = (bf16*)d_out;
    bf16* W16  = (bf16*)((char*)d_out + QSB);                      // 6.29 MB
    unsigned long long* bm = (unsigned long long*)((char*)d_out + QSB + 3 * CC * CC * 2);
    bf16* Kb   = (bf16*)ws;
    bf16* Vt   = (bf16*)(ws + QSB);
    bf16* Wp16 = (bf16*)(ws + QSB);                                // after attn (Vt dead)

    if (ws_size >= 3 * QSB) {
        // Fast path: fused prep (mask bits + Wqkv cvt + X cvt into Ob slot).
        bf16* X16 = (bf16*)(ws + 2 * QSB);
        prep_kernel<<<5632, 256, 0, stream>>>(mask, bm, Wqkv, W16, x, X16);
        qkv_fast_kernel<<<dim3(3072 / 128, 4096 / 128), 256, 0, stream>>>(X16, W16, Qb, Kb, Vt);
        bf16* Ob = (bf16*)(ws + 2 * QSB);   // reuses X16 slot (X16 dead)
        attn_kernel<<<dim3(NN / 128, BB * HH), 256, 0, stream>>>(Qb, Kb, Vt, bm, Ob);
        cvt_bf16_kernel<<<CC * CC / (256 * 8), 256, 0, stream>>>(Wp, Wp16);
        proj_fast_kernel<<<dim3(1024 / 128, 4096 / 128), 256, 0, stream>>>(Ob, Wp16, bias, d_out, d_out, 1);
    } else {
        prep_kernel<<<3584, 256, 0, stream>>>(mask, bm, Wqkv, W16, x, (bf16*)ws);  // X region not launched
        qkv_kernel<<<dim3(3072 / 128, 4096 / 128), 256, 0, stream>>>(x, W16, Qb, Kb, Vt);
        attn_kernel<<<dim3(NN / 128, BB * HH), 256, 0, stream>>>(Qb, Kb, Vt, bm, Qb);
        cvt_bf16_kernel<<<CC * CC / (256 * 8), 256, 0, stream>>>(Wp, Wp16);
        proj_fast_kernel<<<dim3(1024 / 128, 4096 / 128), 256, 0, stream>>>(Qb, Wp16, bias, d_out, ws, 0);
        hipMemcpyAsync(d_out, ws, QSB, hipMemcpyDeviceToDevice, stream);
    }
}

// Round 11
// 262.544 us; speedup vs baseline: 1.0591x; 1.0591x over previous
//
#include <hip/hip_runtime.h>
#include <hip/hip_bf16.h>

typedef __bf16 bf16;
typedef __bf16 bf16x4 __attribute__((ext_vector_type(4)));
typedef __bf16 bf16x8 __attribute__((ext_vector_type(8)));
typedef float f32x4 __attribute__((ext_vector_type(4)));

#define MFMA16(a, b, c) __builtin_amdgcn_mfma_f32_16x16x32_bf16((a), (b), (c), 0, 0, 0)

// Problem constants
#define BB 2
#define HH 16
#define NN 2048
#define CC 1024
#define HD 64
#define NW (NN / 64)   // 64-key words per row = 32

// Q pre-scale: HD^-0.5 * log2(e), so attention can use exp2 directly.
#define QSCALE 0.1803368867f

// ---------------------------------------------------------------------------
// Per-block dtype detectors (512-word scan, L2-hot, wave-uniform result).
// ---------------------------------------------------------------------------
__device__ __forceinline__ int detect_f32_block(const unsigned int* __restrict__ w) {
    __shared__ int bfc_s, tot_s;
    if (threadIdx.x == 0) { bfc_s = 0; tot_s = 0; }
    __syncthreads();
    int bfc = 0, tot = 0;
    for (int i = threadIdx.x; i < 512; i += blockDim.x) {
        unsigned v = w[i];
        if (v != 0u) {
            tot++;
            unsigned e = (v >> 7) & 0xFFu;
            if (e >= 100u && e <= 140u) bfc++;
        }
    }
    atomicAdd(&bfc_s, bfc); atomicAdd(&tot_s, tot);
    __syncthreads();
    int r = (2 * bfc_s < tot_s) ? 1 : 0;
    __syncthreads();
    return r;
}

// mask element size: int64 -> 8, int32/fp32 -> 4, int16/bf16 -> 2, byte -> 1
__device__ __forceinline__ int detect_esz_block(const unsigned int* __restrict__ w) {
    __shared__ int ok8s, ok4s, ok2s;
    if (threadIdx.x == 0) { ok8s = 1; ok4s = 1; ok2s = 1; }
    __syncthreads();
    int ok8 = 1, ok4 = 1, ok2 = 1;
    for (int i = threadIdx.x; i < 512; i += blockDim.x) {
        unsigned v = w[i];
        if ((i & 1) && v != 0u) ok8 = 0;
        if (!(v == 0u || v == 1u || v == 0x3F800000u)) ok4 = 0;
        unsigned lo = v & 0xFFFFu, hi = v >> 16;
        if (!((lo == 0u || lo == 1u || lo == 0x3F80u) &&
              (hi == 0u || hi == 1u || hi == 0x3F80u))) ok2 = 0;
    }
    if (!ok8) atomicAnd(&ok8s, 0);
    if (!ok4) atomicAnd(&ok4s, 0);
    if (!ok2) atomicAnd(&ok2s, 0);
    __syncthreads();
    int r = ok8s ? 8 : (ok4s ? 4 : (ok2s ? 2 : 1));
    __syncthreads();
    return r;
}

// 8-elem fp32->bf16 (or passthrough) convert
__device__ __forceinline__ void cvt8(const void* __restrict__ src, bf16* __restrict__ dst,
                                     size_t e, int f32) {
    bf16x8 v;
    if (f32) {
        const f32x4* S = (const f32x4*)((const float*)src + e);
        f32x4 a = S[0], b = S[1];
        v[0] = (bf16)a[0]; v[1] = (bf16)a[1]; v[2] = (bf16)a[2]; v[3] = (bf16)a[3];
        v[4] = (bf16)b[0]; v[5] = (bf16)b[1]; v[6] = (bf16)b[2]; v[7] = (bf16)b[3];
    } else {
        v = *(const bf16x8*)((const bf16*)src + e);
    }
    *(bf16x8*)&dst[e] = v;
}

// ---------------------------------------------------------------------------
// Kernel: standalone convert (used for Wp after attn frees its slot).
// ---------------------------------------------------------------------------
__global__ __launch_bounds__(256) void cvt_bf16_kernel(const void* __restrict__ src,
                                                       bf16* __restrict__ dst) {
    const int f32 = detect_f32_block((const unsigned int*)src);
    size_t e = ((size_t)blockIdx.x * 256 + threadIdx.x) * 8;
    cvt8(src, dst, e, f32);
}

// ---------------------------------------------------------------------------
// Fused prep kernel: [0,2048) mask->bitmask; [2048,3584) Wqkv cvt;
// [3584,5632) X cvt (tier A only — grid size selects).
// ---------------------------------------------------------------------------
__global__ __launch_bounds__(256) void prep_kernel(const void* __restrict__ maskp,
                                                   unsigned long long* __restrict__ bm,
                                                   const void* __restrict__ Wqkv,
                                                   bf16* __restrict__ W16,
                                                   const void* __restrict__ x,
                                                   bf16* __restrict__ X16) {
    const int bid = blockIdx.x;
    if (bid < 2048) {
        const int esz = detect_esz_block((const unsigned int*)maskp);  // wave-uniform
        const int lane = threadIdx.x & 63;
        const int wave = threadIdx.x >> 6;
        const long wbase = ((long)bid * 4 + wave) * 16;
        for (int i = 0; i < 16; i++) {
            long w = wbase + i;
            long idx = w * 64 + lane;
            bool mk;
            if (esz == 4)      mk = ((const unsigned int*)maskp)[idx] != 0u;
            else if (esz == 2) mk = ((const unsigned short*)maskp)[idx] != 0;
            else if (esz == 8) mk = ((const unsigned long long*)maskp)[idx] != 0ull;
            else               mk = ((const unsigned char*)maskp)[idx] != 0;
            unsigned long long b = __ballot(mk);
            if (lane == 0) bm[w] = b;
        }
    } else if (bid < 3584) {
        const int f32 = detect_f32_block((const unsigned int*)Wqkv);
        size_t e = ((size_t)(bid - 2048) * 256 + threadIdx.x) * 8;
        cvt8(Wqkv, W16, e, f32);
    } else {
        const int f32 = detect_f32_block((const unsigned int*)x);
        size_t e = ((size_t)(bid - 3584) * 256 + threadIdx.x) * 8;
        cvt8(x, X16, e, f32);
    }
}

// ---------------------------------------------------------------------------
// async 16B global -> LDS copy (direct-to-LDS, no VGPR round-trip).
// LDS dest must be wave-uniform base; HW adds lane*16.
// ---------------------------------------------------------------------------
__device__ __forceinline__ void async_cp16(const bf16* g, bf16* l) {
    __builtin_amdgcn_global_load_lds((const __attribute__((address_space(1))) void*)g,
                                     (__attribute__((address_space(3))) void*)l,
                                     16, 0, 0);
}

// ---------------------------------------------------------------------------
// Fast GEMM core: C[128x128] = A[128xK]*B[128xK]^T, K=1024.
// DBUF=0 (qkv, 3 blocks/CU): single 32KB buffer, 2 barriers/iter — implicit
//   cross-block overlap hides latency (R10 showed dbuf HURTS here: 64KB LDS
//   cut residency 3->2 blocks/CU, +15us).
// DBUF=1 (proj, grid=256=1 block/CU): double buffer, 1 barrier/iter — no
//   co-resident block exists, so prefetch-under-compute is the only source
//   of overlap and the extra LDS costs nothing.
// ---------------------------------------------------------------------------
template<int APERM, int DBUF>
__device__ __forceinline__ void gemm_tile_fast(const bf16* __restrict__ Ap,
                                               const bf16* __restrict__ Bp,
                                               int m0, int n0,
                                               bf16* ldsA, bf16* ldsB,
                                               f32x4 acc[4][4]) {
    const int K = 1024;
    const int tid = threadIdx.x, lane = tid & 63, wave = tid >> 6;
    const int l15 = lane & 15, q4 = lane >> 4;
    const int mw = (wave & 1) * 64, nw = (wave >> 1) * 64;

    #pragma unroll
    for (int i = 0; i < 4; i++)
        #pragma unroll
        for (int j = 0; j < 4; j++) {
            f32x4 z = {0.f, 0.f, 0.f, 0.f};
            acc[i][j] = z;
        }

    const int rA = tid >> 3;          // row within 32-row issue group
    const int colc = (tid & 7) << 3;  // col (elems) within 64-wide tile

    auto stage = [&](int kt, int buf) {
        #pragma unroll
        for (int i = 0; i < 4; i++) {
            int r = i * 32 + rA;
            size_t ae;
            if (APERM) {
                int m = m0 + r;
                ae = (((size_t)(m >> 11) * HH + kt) * NN + (m & (NN - 1))) * HD + colc;
            } else {
                ae = (size_t)(m0 + r) * K + kt * 64 + colc;
            }
            async_cp16(&Ap[ae], &ldsA[buf * 8192 + i * 2048 + wave * 512]);
            size_t be = (size_t)(n0 + r) * K + kt * 64 + colc;
            async_cp16(&Bp[be], &ldsB[buf * 8192 + i * 2048 + wave * 512]);
        }
    };

    auto compute = [&](const bf16* lA, const bf16* lB) {
        #pragma unroll
        for (int ks = 0; ks < 2; ks++) {
            bf16x8 af[4], bfr[4];
            #pragma unroll
            for (int i = 0; i < 4; i++)
                af[i] = *(const bf16x8*)&lA[(mw + i * 16 + l15) * 64 + ks * 32 + q4 * 8];
            #pragma unroll
            for (int j = 0; j < 4; j++)
                bfr[j] = *(const bf16x8*)&lB[(nw + j * 16 + l15) * 64 + ks * 32 + q4 * 8];
            #pragma unroll
            for (int i = 0; i < 4; i++)
                #pragma unroll
                for (int j = 0; j < 4; j++)
                    acc[i][j] = MFMA16(af[i], bfr[j], acc[i][j]);
        }
    };

    if (DBUF) {
        stage(0, 0);
        __syncthreads();   // drain tile 0
        for (int kt = 0; kt < 16; ++kt) {
            if (kt < 15) stage(kt + 1, (kt + 1) & 1);
            compute(&ldsA[(kt & 1) * 8192], &ldsB[(kt & 1) * 8192]);
            __syncthreads();   // drains prefetch (vmcnt 0) + syncs buffer reuse
        }
    } else {
        for (int kt = 0; kt < 16; ++kt) {
            __syncthreads();   // prior iter's ds_reads complete before overwrite
            stage(kt, 0);
            __syncthreads();   // vmcnt(0) drain: staged tile visible
            compute(ldsA, ldsB);
        }
    }
}

// ---------------------------------------------------------------------------
// Legacy GEMM core (register-staged, in-loop fp32->bf16): tier-B qkv only.
// ---------------------------------------------------------------------------
__device__ __forceinline__ void gemm_tile(const void* __restrict__ Ap,
                                          const bf16* __restrict__ Bp,
                                          int K, int m0, int n0,
                                          int af32, int aperm,
                                          bf16* ldsA, bf16* ldsB,
                                          f32x4 acc[4][4]) {
    const int tid = threadIdx.x, lane = tid & 63, wave = tid >> 6;
    const int l15 = lane & 15, q4 = lane >> 4;
    const int mw = (wave & 1) * 64, nw = (wave >> 1) * 64;

    #pragma unroll
    for (int i = 0; i < 4; i++)
        #pragma unroll
        for (int j = 0; j < 4; j++) {
            f32x4 z = {0.f, 0.f, 0.f, 0.f};
            acc[i][j] = z;
        }

    const int nkt = K / 64;
    for (int kt = 0; kt < nkt; ++kt) {
        __syncthreads();
        #pragma unroll
        for (int c0 = 0; c0 < 4; c0++) {
            int c = tid + c0 * 256;               // 1024 chunks of 8 elems
            int r = c >> 3, kc = (c & 7) << 3;
            size_t ae;
            if (aperm) {
                int m = m0 + r;
                ae = (((size_t)(m >> 11) * HH + kt) * NN + (m & (NN - 1))) * HD + kc;
            } else {
                ae = (size_t)(m0 + r) * K + kt * 64 + kc;
            }
            bf16x8 av;
            if (af32) {
                const f32x4* Af = (const f32x4*)((const float*)Ap + ae);
                f32x4 a0 = Af[0], a1 = Af[1];
                av[0] = (bf16)a0[0]; av[1] = (bf16)a0[1]; av[2] = (bf16)a0[2]; av[3] = (bf16)a0[3];
                av[4] = (bf16)a1[0]; av[5] = (bf16)a1[1]; av[6] = (bf16)a1[2]; av[7] = (bf16)a1[3];
            } else {
                av = *(const bf16x8*)((const bf16*)Ap + ae);
            }
            *(bf16x8*)&ldsA[r * 72 + kc] = av;
            size_t be = (size_t)(n0 + r) * K + kt * 64 + kc;
            *(bf16x8*)&ldsB[r * 72 + kc] = *(const bf16x8*)&Bp[be];
        }
        __syncthreads();
        #pragma unroll
        for (int ks = 0; ks < 2; ks++) {
            bf16x8 af[4], bfr[4];
            #pragma unroll
            for (int i = 0; i < 4; i++)
                af[i] = *(bf16x8*)&ldsA[(mw + i * 16 + l15) * 72 + ks * 32 + q4 * 8];
            #pragma unroll
            for (int j = 0; j < 4; j++)
                bfr[j] = *(bf16x8*)&ldsB[(nw + j * 16 + l15) * 72 + ks * 32 + q4 * 8];
            #pragma unroll
            for (int i = 0; i < 4; i++)
                #pragma unroll
                for (int j = 0; j < 4; j++)
                    acc[i][j] = MFMA16(af[i], bfr[j], acc[i][j]);
        }
    }
}

// ---------------------------------------------------------------------------
// Shared QKV epilogue. 'which' is block-uniform (n0 multiple of 128).
// V blocks pack 4 consecutive-m values into one b64 store.
// ---------------------------------------------------------------------------
__device__ __forceinline__ void qkv_epilogue(f32x4 acc[4][4], int m0, int n0,
                                             bf16* __restrict__ Qb,
                                             bf16* __restrict__ Kb,
                                             bf16* __restrict__ Vt) {
    const int tid = threadIdx.x, lane = tid & 63, wave = tid >> 6;
    const int l15 = lane & 15, q4 = lane >> 4;
    const int mw = (wave & 1) * 64, nw = (wave >> 1) * 64;

    if (n0 >= 2 * CC) {
        // V region: packed bf16x4 stores along nq
        #pragma unroll
        for (int i = 0; i < 4; i++) {
            #pragma unroll
            for (int j = 0; j < 4; j++) {
                int n = n0 - 2 * CC + nw + j * 16 + l15;   // 0..1023
                int h = n >> 6, d = n & 63;
                int mbase = m0 + mw + i * 16 + q4 * 4;     // 4 consecutive m, no 2048-cross
                int b = mbase >> 11, nq = mbase & (NN - 1);
                bf16x4 pv;
                #pragma unroll
                for (int r = 0; r < 4; r++) pv[r] = (bf16)acc[i][j][r];
                *(bf16x4*)&Vt[((size_t)(b * HH + h) * HD + d) * NN + nq] = pv;
            }
        }
    } else {
        const int isK = n0 >= CC;
        #pragma unroll
        for (int i = 0; i < 4; i++) {
            #pragma unroll
            for (int j = 0; j < 4; j++) {
                #pragma unroll
                for (int r = 0; r < 4; r++) {
                    int m = m0 + mw + i * 16 + q4 * 4 + r;
                    int n = (n0 & (CC - 1)) + nw + j * 16 + l15;
                    int h = n >> 6, d = n & 63;
                    int b = m >> 11, nq = m & (NN - 1);
                    size_t bh = (size_t)(b * HH + h);
                    float v = acc[i][j][r];
                    if (isK) Kb[(bh * NN + nq) * HD + d] = (bf16)v;
                    else     Qb[(bh * NN + nq) * HD + d] = (bf16)(v * QSCALE);
                }
            }
        }
    }
}

// ---------------------------------------------------------------------------
// Kernel 1a: QKV projection, fast path (A pre-converted to bf16).
// Single-buffer core (32KB LDS -> 3 blocks/CU implicit overlap).
// ---------------------------------------------------------------------------
__global__ __launch_bounds__(256, 2) void qkv_fast_kernel(const bf16* __restrict__ X16,
                                                          const bf16* __restrict__ Wqkv,
                                                          bf16* __restrict__ Qb,
                                                          bf16* __restrict__ Kb,
                                                          bf16* __restrict__ Vt) {
    __shared__ alignas(16) bf16 ldsA[128 * 64];
    __shared__ alignas(16) bf16 ldsB[128 * 64];
    f32x4 acc[4][4];
    const int m0 = blockIdx.y * 128, n0 = blockIdx.x * 128;
    gemm_tile_fast<0, 0>(X16, Wqkv, m0, n0, ldsA, ldsB, acc);
    qkv_epilogue(acc, m0, n0, Qb, Kb, Vt);
}

// ---------------------------------------------------------------------------
// Kernel 1b: QKV projection, legacy path (fp32/bf16 A, reg staging). Tier B.
// ---------------------------------------------------------------------------
__global__ __launch_bounds__(256, 2) void qkv_kernel(const void* __restrict__ X,
                                                     const bf16* __restrict__ Wqkv,
                                                     bf16* __restrict__ Qb,
                                                     bf16* __restrict__ Kb,
                                                     bf16* __restrict__ Vt) {
    __shared__ alignas(16) bf16 ldsA[128 * 72];
    __shared__ alignas(16) bf16 ldsB[128 * 72];
    const int f32 = detect_f32_block((const unsigned int*)X);
    f32x4 acc[4][4];
    const int m0 = blockIdx.y * 128, n0 = blockIdx.x * 128;
    gemm_tile(X, Wqkv, 1024, m0, n0, f32, 0, ldsA, ldsB, acc);
    qkv_epilogue(acc, m0, n0, Qb, Kb, Vt);
}

// ---------------------------------------------------------------------------
// Kernel 2: flash attention v12 (unchanged from R9 measurement).
// ---------------------------------------------------------------------------
__global__ __launch_bounds__(256, 2) void attn_kernel(const bf16* __restrict__ Qb,
                                                      const bf16* __restrict__ Kb,
                                                      const bf16* __restrict__ Vt,
                                                      const unsigned long long* __restrict__ bm,
                                                      bf16* __restrict__ Ob) {
    __shared__ alignas(16) bf16 Kt[2][64 * 64];
    __shared__ alignas(16) bf16 Vs[2][64 * 64];    // [d][key], swizzled chunks
    __shared__ alignas(16) bf16 Ps[4][32 * 72];    // per-wave P tile (swizzled)

    // XCD swizzle: 512 blocks; XCD x gets logical blocks [x*64, x*64+64) = 4 bh
    const int wg = blockIdx.y * (NN / 128) + blockIdx.x;   // 512 blocks
    const int swzb = (wg & 7) * 64 + (wg >> 3);            // bijective (512%8==0)
    const int bh = swzb >> 4;
    const int qb = (swzb & 15) * 128;
    const int b = bh >> 4;
    const int tid = threadIdx.x, lane = tid & 63, wave = tid >> 6;
    const int l15 = lane & 15, q4 = lane >> 4;

    const bf16* Qp = Qb + (size_t)bh * NN * HD;
    const bf16* Kp = Kb + (size_t)bh * NN * HD;
    const bf16* Vp = Vt + (size_t)bh * HD * NN;

    // staging geometry: chunk g = wave*64 + lane + s2*256; row = g>>3,
    // logical chunk fetched = (g&7)^(row&7) (XOR swizzle on global source).
    const int srow0 = (wave * 64 + lane) >> 3;
    const int sc0 = ((wave * 64 + lane) & 7) ^ (srow0 & 7);
    const int srow1 = (wave * 64 + lane + 256) >> 3;
    const int sc1 = ((wave * 64 + lane + 256) & 7) ^ (srow1 & 7);

    // Q fragments for both 16-row halves: rows qrb + h*16 + l15
    const int qrb = qb + wave * 32;
    bf16x8 qf[2][2];
    #pragma unroll
    for (int h = 0; h < 2; h++)
        #pragma unroll
        for (int s = 0; s < 2; s++)
            qf[h][s] = *(const bf16x8*)&Qp[(size_t)(qrb + h * 16 + l15) * HD + s * 32 + q4 * 8];

    // ones B-fragment for the denominator MFMA
    bf16x8 ones;
    #pragma unroll
    for (int i = 0; i < 8; i++) ones[i] = (bf16)1.0f;

    const f32x4 FZ = {0.f, 0.f, 0.f, 0.f};

    f32x4 o[2][4];
    f32x4 lacc[2] = {FZ, FZ};
    #pragma unroll
    for (int h = 0; h < 2; h++)
        #pragma unroll
        for (int jd = 0; jd < 4; jd++) o[h][jd] = FZ;

    // bitmask: this lane's q-row word (S^T: one q per lane, l15) per half
    const unsigned long long* bmr = bm + ((size_t)b * NN + qrb + l15) * NW;

    bf16* Pw = &Ps[wave][0];
    const int swzP = (l15 >> 1) & 7;          // P block swizzle for this q-row
    const int pwrow = l15 * 72;               // P row base (elems), half adds 16*72

    // swizzled LDS read chunk offsets (elems) for K/V fragment loads
    const int rc0 = ((0 * 4 + q4) ^ (l15 & 7)) * 8;   // ks=0
    const int rc1 = ((1 * 4 + q4) ^ (l15 & 7)) * 8;   // ks=1

    // ---- helper lambdas (all static indexing after inlining) ----
    auto QK = [&](const bf16* KtC, f32x4 (&sj)[2][4]) {
        #pragma unroll
        for (int j = 0; j < 4; j++) {
            bf16x8 kf0 = *(const bf16x8*)&KtC[(j * 16 + l15) * 64 + rc0];
            sj[0][j] = MFMA16(kf0, qf[0][0], FZ);
            sj[1][j] = MFMA16(kf0, qf[1][0], FZ);
            bf16x8 kf1 = *(const bf16x8*)&KtC[(j * 16 + l15) * 64 + rc1];
            sj[0][j] = MFMA16(kf1, qf[0][1], sj[0][j]);
            sj[1][j] = MFMA16(kf1, qf[1][1], sj[1][j]);
        }
    };
    auto EXPSTORE = [&](f32x4 (&sj)[2][4], unsigned (&s0)[2], unsigned (&s1)[2]) {
        #pragma unroll
        for (int h = 0; h < 2; h++) {
            #pragma unroll
            for (int j = 0; j < 4; j++) {
                unsigned w = (j < 2) ? s0[h] : s1[h];
                unsigned ws = (j & 1) ? (w >> 16) : w;
                bf16x4 pv;
                #pragma unroll
                for (int r = 0; r < 4; r++) {
                    unsigned bit = (ws >> r) & 1u;
                    float ex = __builtin_amdgcn_exp2f(sj[h][j][r]);
                    pv[r] = (bf16)(bit ? ex : 0.f);
                }
                const int blk = (2 * j + (q4 >> 1)) ^ swzP;
                *(bf16x4*)&Pw[(h * 16 * 72) + pwrow + blk * 8 + (q4 & 1) * 4] = pv;
            }
        }
    };
    auto PV = [&](const bf16* VsC) {
        __builtin_amdgcn_s_setprio(1);
        #pragma unroll
        for (int ks = 0; ks < 2; ks++) {
            const int psw = ((4 * ks + q4) ^ swzP) * 8;
            bf16x8 pf0 = *(bf16x8*)&Pw[pwrow + psw];
            bf16x8 pf1 = *(bf16x8*)&Pw[(16 * 72) + pwrow + psw];
            lacc[0] = MFMA16(pf0, ones, lacc[0]);
            lacc[1] = MFMA16(pf1, ones, lacc[1]);
            const int rcv = (ks ? rc1 : rc0);
            #pragma unroll
            for (int jd = 0; jd < 4; jd++) {
                bf16x8 vf = *(const bf16x8*)&VsC[(jd * 16 + l15) * 64 + rcv];
                o[0][jd] = MFMA16(pf0, vf, o[0][jd]);
                o[1][jd] = MFMA16(pf1, vf, o[1][jd]);
            }
        }
        __builtin_amdgcn_s_setprio(0);
    };

    // ---- prologue: stage tile 0 (K and V), mask(0); then K1 + QK(0)
    async_cp16(&Kp[(size_t)srow0 * HD + sc0 * 8], &Kt[0][(wave * 64) * 8]);
    async_cp16(&Kp[(size_t)srow1 * HD + sc1 * 8], &Kt[0][(wave * 64 + 256) * 8]);
    async_cp16(&Vp[(size_t)srow0 * NN + sc0 * 8], &Vs[0][(wave * 64) * 8]);
    async_cp16(&Vp[(size_t)srow1 * NN + sc1 * 8], &Vs[0][(wave * 64 + 256) * 8]);
    unsigned long long mwreg[2];
    #pragma unroll
    for (int h = 0; h < 2; h++) mwreg[h] = bmr[(size_t)h * 16 * NW];
    __syncthreads();   // drain tile-0 loads

    // prefetch K tile 1 (slot 1 untouched so far)
    async_cp16(&Kp[(size_t)(64 + srow0) * HD + sc0 * 8], &Kt[1][(wave * 64) * 8]);
    async_cp16(&Kp[(size_t)(64 + srow1) * HD + sc1 * 8], &Kt[1][(wave * 64 + 256) * 8]);

    f32x4 sjA[2][4], sjB[2][4];
    unsigned mA0[2], mA1[2], mB0[2], mB1[2];

    QK(&Kt[0][0], sjA);                         // S for tile 0
    #pragma unroll
    for (int h = 0; h < 2; h++) {
        mA0[h] = ((unsigned)mwreg[h]) >> (q4 * 4);
        mA1[h] = ((unsigned)(mwreg[h] >> 32)) >> (q4 * 4);
        mwreg[h] = bmr[(size_t)h * 16 * NW + 1];
    }
    __syncthreads();   // drain K tile-1 loads (all waves' QK(0) reads done)

    // ---- skewed steady-state: STEP(kt) = QK(kt) || finish(kt-1)
    // Slot usage inside STEP(kt):  K write (kt+1)&1 | K read kt&1
    //                              V write kt&1     | V read (kt-1)&1   (disjoint)
    auto STEP = [&](int kt, f32x4 (&sjP)[2][4], f32x4 (&sjC)[2][4],
                    unsigned (&s0P)[2], unsigned (&s1P)[2],
                    unsigned (&s0N)[2], unsigned (&s1N)[2]) {
        const int ktn = (kt + 1) & (NN / 64 - 1);   // kt=31 wraps (garbage ok)
        // 1. K prefetch for kt+1 (slot (kt+1)&1; last readers ran in STEP(kt-1))
        {
            bf16* KtN = &Kt[(kt + 1) & 1][0];
            async_cp16(&Kp[(size_t)(ktn * 64 + srow0) * HD + sc0 * 8], &KtN[(wave * 64) * 8]);
            async_cp16(&Kp[(size_t)(ktn * 64 + srow1) * HD + sc1 * 8], &KtN[(wave * 64 + 256) * 8]);
        }
        // 2. V prefetch for THIS tile kt (slot kt&1; consumed by PV(kt) next
        //    STEP after this step's barrier; prior content V[kt-2] done in
        //    STEP(kt-1) behind its barrier; disjoint from PV's read slot).
        {
            bf16* VsN = &Vs[kt & 1][0];
            async_cp16(&Vp[(size_t)srow0 * NN + kt * 64 + sc0 * 8], &VsN[(wave * 64) * 8]);
            async_cp16(&Vp[(size_t)srow1 * NN + kt * 64 + sc1 * 8], &VsN[(wave * 64 + 256) * 8]);
        }
        // 3. QK(kt): MFMAs issue; results not consumed until next STEP
        QK(&Kt[kt & 1][0], sjC);
        // 4+5. finish tile kt-1 in the MFMA shadow: exp/mask -> P -> PV
        EXPSTORE(sjP, s0P, s1P);
        PV(&Vs[(kt - 1) & 1][0]);
        // 6. mask shifts for tile kt (consumed next STEP); prefetch mask kt+1
        #pragma unroll
        for (int h = 0; h < 2; h++) {
            s0N[h] = ((unsigned)mwreg[h]) >> (q4 * 4);
            s1N[h] = ((unsigned)(mwreg[h] >> 32)) >> (q4 * 4);
            mwreg[h] = bmr[(size_t)h * 16 * NW + ktn];
        }
        // 7. single barrier: drains K/V prefetch, syncs buffer reuse
        __syncthreads();
    };

    for (int kt = 1; kt <= 29; kt += 2) {
        STEP(kt,     sjA, sjB, mA0, mA1, mB0, mB1);
        STEP(kt + 1, sjB, sjA, mB0, mB1, mA0, mA1);
    }
    STEP(31, sjA, sjB, mA0, mA1, mB0, mB1);

    // ---- tail: finish tile 31 (V[31] staged in slot 1, drained at STEP(31))
    EXPSTORE(sjB, mB0, mB1);
    PV(&Vs[1][0]);

    // normalize + write (lacc[h][r] = rowsum for row h*16+q4*4+r)
    #pragma unroll
    for (int h = 0; h < 2; h++) {
        float rl[4];
        #pragma unroll
        for (int r = 0; r < 4; r++) rl[r] = 1.0f / lacc[h][r];
        #pragma unroll
        for (int jd = 0; jd < 4; jd++) {
            #pragma unroll
            for (int r = 0; r < 4; r++) {
                int q = qrb + h * 16 + q4 * 4 + r;
                int d = jd * 16 + l15;
                Ob[((size_t)bh * NN + q) * HD + d] = (bf16)(o[h][jd][r] * rl[r]);
            }
        }
    }
}

// ---------------------------------------------------------------------------
// Kernel 3: output projection + bias. DBUF=1 core (grid=256 blocks = 1/CU:
// no co-resident block, so explicit prefetch is the only latency hiding;
// 64KB LDS costs nothing at 1 block/CU).
// ---------------------------------------------------------------------------
__global__ __launch_bounds__(256, 2) void proj_fast_kernel(const bf16* __restrict__ Ain,
                                                           const bf16* __restrict__ Wp16,
                                                           const void* __restrict__ biasp,
                                                           void* __restrict__ Outd,
                                                           void* __restrict__ Tmp,
                                                           int direct) {
    __shared__ alignas(16) bf16 ldsA[2 * 128 * 64];
    __shared__ alignas(16) bf16 ldsB[2 * 128 * 64];
    const int f32 = detect_f32_block((const unsigned int*)biasp);
    f32x4 acc[4][4];
    const int m0 = blockIdx.y * 128, n0 = blockIdx.x * 128;
    gemm_tile_fast<1, 1>(Ain, Wp16, m0, n0, ldsA, ldsB, acc);

    const int tid = threadIdx.x, lane = tid & 63, wave = tid >> 6;
    const int l15 = lane & 15, q4 = lane >> 4;
    const int mw = (wave & 1) * 64, nw = (wave >> 1) * 64;
    #pragma unroll
    for (int i = 0; i < 4; i++) {
        #pragma unroll
        for (int j = 0; j < 4; j++) {
            #pragma unroll
            for (int r = 0; r < 4; r++) {
                int m = m0 + mw + i * 16 + q4 * 4 + r;
                int n = n0 + nw + j * 16 + l15;
                float bv = f32 ? ((const float*)biasp)[n] : (float)((const bf16*)biasp)[n];
                float val = acc[i][j][r] + bv;
                size_t idx = (size_t)m * CC + n;
                if (f32) {
                    if (direct || idx >= (size_t)2097152)   // byte off >= 8MB
                        ((float*)Outd)[idx] = val;
                    else
                        ((float*)Tmp)[idx] = val;
                } else {
                    if (direct) ((bf16*)Outd)[idx] = (bf16)val;
                    else        ((bf16*)Tmp)[idx] = (bf16)val;
                }
            }
        }
    }
}

// ---------------------------------------------------------------------------
// Memory map (fp32 output established => d_out = 16.78 MB):
//  d_out: [0, 8.39M)        Q scratch (tier B: attention O in-place)
//         [8.39M, 14.68M)   W_qkv bf16 (dead after qkv)
//         [14.68M, 15.73M)  key bitmask (dead after attn)
//  ws:    [0, 8.39M)        Kb (tier B: proj low-half staging after attn)
//         [8.39M, 16.78M)   Vt; after attn: Wp16 bf16 (2.1 MB) at 8.39M
//         tier A adds @16.78M: X16 bf16 (dead after qkv) then Ob (attn out)
// ---------------------------------------------------------------------------
extern "C" void kernel_launch(void* const* d_in, const int* in_sizes, int n_in,
                              void* d_out, int out_size, void* d_ws, size_t ws_size,
                              hipStream_t stream) {
    const void* x    = d_in[0];
    const void* mask = d_in[1];
    const void* Wqkv = d_in[2];
    const void* Wp   = d_in[3];
    const void* bias = d_in[4];

    char* ws = (char*)d_ws;
    const size_t QS  = (size_t)BB * HH * NN * HD;     // 4,194,304 elems
    const size_t QSB = QS * sizeof(bf16);             // 8,388,608 bytes
    bf16* Qb   = (bf16*)d_out;
    bf16* W16  = (bf16*)((char*)d_out + QSB);                      // 6.29 MB
    unsigned long long* bm = (unsigned long long*)((char*)d_out + QSB + 3 * CC * CC * 2);
    bf16* Kb   = (bf16*)ws;
    bf16* Vt   = (bf16*)(ws + QSB);
    bf16* Wp16 = (bf16*)(ws + QSB);                                // after attn (Vt dead)

    if (ws_size >= 3 * QSB) {
        // Fast path: fused prep (mask bits + Wqkv cvt + X cvt into Ob slot).
        bf16* X16 = (bf16*)(ws + 2 * QSB);
        prep_kernel<<<5632, 256, 0, stream>>>(mask, bm, Wqkv, W16, x, X16);
        qkv_fast_kernel<<<dim3(3072 / 128, 4096 / 128), 256, 0, stream>>>(X16, W16, Qb, Kb, Vt);
        bf16* Ob = (bf16*)(ws + 2 * QSB);   // reuses X16 slot (X16 dead)
        attn_kernel<<<dim3(NN / 128, BB * HH), 256, 0, stream>>>(Qb, Kb, Vt, bm, Ob);
        cvt_bf16_kernel<<<CC * CC / (256 * 8), 256, 0, stream>>>(Wp, Wp16);
        proj_fast_kernel<<<dim3(1024 / 128, 4096 / 128), 256, 0, stream>>>(Ob, Wp16, bias, d_out, d_out, 1);
    } else {
        prep_kernel<<<3584, 256, 0, stream>>>(mask, bm, Wqkv, W16, x, (bf16*)ws);  // X region not launched
        qkv_kernel<<<dim3(3072 / 128, 4096 / 128), 256, 0, stream>>>(x, W16, Qb, Kb, Vt);
        attn_kernel<<<dim3(NN / 128, BB * HH), 256, 0, stream>>>(Qb, Kb, Vt, bm, Qb);
        cvt_bf16_kernel<<<CC * CC / (256 * 8), 256, 0, stream>>>(Wp, Wp16);
        proj_fast_kernel<<<dim3(1024 / 128, 4096 / 128), 256, 0, stream>>>(Qb, Wp16, bias, d_out, ws, 0);
        hipMemcpyAsync(d_out, ws, QSB, hipMemcpyDeviceToDevice, stream);
    }
}

// Round 12
// 254.263 us; speedup vs baseline: 1.0936x; 1.0326x over previous
//
#include <hip/hip_runtime.h>
#include <hip/hip_bf16.h>

typedef __bf16 bf16;
typedef __bf16 bf16x4 __attribute__((ext_vector_type(4)));
typedef __bf16 bf16x8 __attribute__((ext_vector_type(8)));
typedef float f32x4 __attribute__((ext_vector_type(4)));

#define MFMA16(a, b, c) __builtin_amdgcn_mfma_f32_16x16x32_bf16((a), (b), (c), 0, 0, 0)

// Problem constants
#define BB 2
#define HH 16
#define NN 2048
#define CC 1024
#define HD 64
#define NW (NN / 64)   // 64-key words per row = 32

// Q pre-scale: HD^-0.5 * log2(e), so attention can use exp2 directly.
#define QSCALE 0.1803368867f

// ---------------------------------------------------------------------------
// Per-block dtype detectors (512-word scan, L2-hot, wave-uniform result).
// ---------------------------------------------------------------------------
__device__ __forceinline__ int detect_f32_block(const unsigned int* __restrict__ w) {
    __shared__ int bfc_s, tot_s;
    if (threadIdx.x == 0) { bfc_s = 0; tot_s = 0; }
    __syncthreads();
    int bfc = 0, tot = 0;
    for (int i = threadIdx.x; i < 512; i += blockDim.x) {
        unsigned v = w[i];
        if (v != 0u) {
            tot++;
            unsigned e = (v >> 7) & 0xFFu;
            if (e >= 100u && e <= 140u) bfc++;
        }
    }
    atomicAdd(&bfc_s, bfc); atomicAdd(&tot_s, tot);
    __syncthreads();
    int r = (2 * bfc_s < tot_s) ? 1 : 0;
    __syncthreads();
    return r;
}

// mask element size: int64 -> 8, int32/fp32 -> 4, int16/bf16 -> 2, byte -> 1
__device__ __forceinline__ int detect_esz_block(const unsigned int* __restrict__ w) {
    __shared__ int ok8s, ok4s, ok2s;
    if (threadIdx.x == 0) { ok8s = 1; ok4s = 1; ok2s = 1; }
    __syncthreads();
    int ok8 = 1, ok4 = 1, ok2 = 1;
    for (int i = threadIdx.x; i < 512; i += blockDim.x) {
        unsigned v = w[i];
        if ((i & 1) && v != 0u) ok8 = 0;
        if (!(v == 0u || v == 1u || v == 0x3F800000u)) ok4 = 0;
        unsigned lo = v & 0xFFFFu, hi = v >> 16;
        if (!((lo == 0u || lo == 1u || lo == 0x3F80u) &&
              (hi == 0u || hi == 1u || hi == 0x3F80u))) ok2 = 0;
    }
    if (!ok8) atomicAnd(&ok8s, 0);
    if (!ok4) atomicAnd(&ok4s, 0);
    if (!ok2) atomicAnd(&ok2s, 0);
    __syncthreads();
    int r = ok8s ? 8 : (ok4s ? 4 : (ok2s ? 2 : 1));
    __syncthreads();
    return r;
}

// 8-elem fp32->bf16 (or passthrough) convert
__device__ __forceinline__ void cvt8(const void* __restrict__ src, bf16* __restrict__ dst,
                                     size_t e, int f32) {
    bf16x8 v;
    if (f32) {
        const f32x4* S = (const f32x4*)((const float*)src + e);
        f32x4 a = S[0], b = S[1];
        v[0] = (bf16)a[0]; v[1] = (bf16)a[1]; v[2] = (bf16)a[2]; v[3] = (bf16)a[3];
        v[4] = (bf16)b[0]; v[5] = (bf16)b[1]; v[6] = (bf16)b[2]; v[7] = (bf16)b[3];
    } else {
        v = *(const bf16x8*)((const bf16*)src + e);
    }
    *(bf16x8*)&dst[e] = v;
}

// ---------------------------------------------------------------------------
// Kernel: standalone convert (fallback: Wp after attn frees the Vt slot).
// ---------------------------------------------------------------------------
__global__ __launch_bounds__(256) void cvt_bf16_kernel(const void* __restrict__ src,
                                                       bf16* __restrict__ dst) {
    const int f32 = detect_f32_block((const unsigned int*)src);
    size_t e = ((size_t)blockIdx.x * 256 + threadIdx.x) * 8;
    cvt8(src, dst, e, f32);
}

// ---------------------------------------------------------------------------
// Fused prep kernel: [0,2048) mask->bitmask; [2048,3584) Wqkv cvt;
// [3584,5632) X cvt; [5632,6144) Wp cvt. Grid size selects which regions
// run (tier B: 3584; tier A no-spare-ws: 5632; tier A spare-ws: 6144).
// All regions are independent (disjoint inputs/outputs).
// ---------------------------------------------------------------------------
__global__ __launch_bounds__(256) void prep_kernel(const void* __restrict__ maskp,
                                                   unsigned long long* __restrict__ bm,
                                                   const void* __restrict__ Wqkv,
                                                   bf16* __restrict__ W16,
                                                   const void* __restrict__ x,
                                                   bf16* __restrict__ X16,
                                                   const void* __restrict__ Wp,
                                                   bf16* __restrict__ Wp16) {
    const int bid = blockIdx.x;
    if (bid < 2048) {
        const int esz = detect_esz_block((const unsigned int*)maskp);  // wave-uniform
        const int lane = threadIdx.x & 63;
        const int wave = threadIdx.x >> 6;
        const long wbase = ((long)bid * 4 + wave) * 16;
        for (int i = 0; i < 16; i++) {
            long w = wbase + i;
            long idx = w * 64 + lane;
            bool mk;
            if (esz == 4)      mk = ((const unsigned int*)maskp)[idx] != 0u;
            else if (esz == 2) mk = ((const unsigned short*)maskp)[idx] != 0;
            else if (esz == 8) mk = ((const unsigned long long*)maskp)[idx] != 0ull;
            else               mk = ((const unsigned char*)maskp)[idx] != 0;
            unsigned long long b = __ballot(mk);
            if (lane == 0) bm[w] = b;
        }
    } else if (bid < 3584) {
        const int f32 = detect_f32_block((const unsigned int*)Wqkv);
        size_t e = ((size_t)(bid - 2048) * 256 + threadIdx.x) * 8;
        cvt8(Wqkv, W16, e, f32);
    } else if (bid < 5632) {
        const int f32 = detect_f32_block((const unsigned int*)x);
        size_t e = ((size_t)(bid - 3584) * 256 + threadIdx.x) * 8;
        cvt8(x, X16, e, f32);
    } else {
        const int f32 = detect_f32_block((const unsigned int*)Wp);
        size_t e = ((size_t)(bid - 5632) * 256 + threadIdx.x) * 8;
        cvt8(Wp, Wp16, e, f32);
    }
}

// ---------------------------------------------------------------------------
// async 16B global -> LDS copy (direct-to-LDS, no VGPR round-trip).
// LDS dest must be wave-uniform base; HW adds lane*16.
// ---------------------------------------------------------------------------
__device__ __forceinline__ void async_cp16(const bf16* g, bf16* l) {
    __builtin_amdgcn_global_load_lds((const __attribute__((address_space(1))) void*)g,
                                     (__attribute__((address_space(3))) void*)l,
                                     16, 0, 0);
}

// ---------------------------------------------------------------------------
// Fast GEMM core: C[128x128] = A[128xK]*B[128xK]^T, K=1024.
// DBUF=0 (qkv, 3 blocks/CU): single 32KB buffer, 2 barriers/iter — implicit
//   cross-block overlap hides latency (R10: dbuf HURTS here, -occupancy).
// DBUF=1 (proj, grid=256=1 block/CU): double buffer, 1 barrier/iter.
// ---------------------------------------------------------------------------
template<int APERM, int DBUF>
__device__ __forceinline__ void gemm_tile_fast(const bf16* __restrict__ Ap,
                                               const bf16* __restrict__ Bp,
                                               int m0, int n0,
                                               bf16* ldsA, bf16* ldsB,
                                               f32x4 acc[4][4]) {
    const int K = 1024;
    const int tid = threadIdx.x, lane = tid & 63, wave = tid >> 6;
    const int l15 = lane & 15, q4 = lane >> 4;
    const int mw = (wave & 1) * 64, nw = (wave >> 1) * 64;

    #pragma unroll
    for (int i = 0; i < 4; i++)
        #pragma unroll
        for (int j = 0; j < 4; j++) {
            f32x4 z = {0.f, 0.f, 0.f, 0.f};
            acc[i][j] = z;
        }

    const int rA = tid >> 3;          // row within 32-row issue group
    const int colc = (tid & 7) << 3;  // col (elems) within 64-wide tile

    auto stage = [&](int kt, int buf) {
        #pragma unroll
        for (int i = 0; i < 4; i++) {
            int r = i * 32 + rA;
            size_t ae;
            if (APERM) {
                int m = m0 + r;
                ae = (((size_t)(m >> 11) * HH + kt) * NN + (m & (NN - 1))) * HD + colc;
            } else {
                ae = (size_t)(m0 + r) * K + kt * 64 + colc;
            }
            async_cp16(&Ap[ae], &ldsA[buf * 8192 + i * 2048 + wave * 512]);
            size_t be = (size_t)(n0 + r) * K + kt * 64 + colc;
            async_cp16(&Bp[be], &ldsB[buf * 8192 + i * 2048 + wave * 512]);
        }
    };

    auto compute = [&](const bf16* lA, const bf16* lB) {
        #pragma unroll
        for (int ks = 0; ks < 2; ks++) {
            bf16x8 af[4], bfr[4];
            #pragma unroll
            for (int i = 0; i < 4; i++)
                af[i] = *(const bf16x8*)&lA[(mw + i * 16 + l15) * 64 + ks * 32 + q4 * 8];
            #pragma unroll
            for (int j = 0; j < 4; j++)
                bfr[j] = *(const bf16x8*)&lB[(nw + j * 16 + l15) * 64 + ks * 32 + q4 * 8];
            #pragma unroll
            for (int i = 0; i < 4; i++)
                #pragma unroll
                for (int j = 0; j < 4; j++)
                    acc[i][j] = MFMA16(af[i], bfr[j], acc[i][j]);
        }
    };

    if (DBUF) {
        stage(0, 0);
        __syncthreads();   // drain tile 0
        for (int kt = 0; kt < 16; ++kt) {
            if (kt < 15) stage(kt + 1, (kt + 1) & 1);
            compute(&ldsA[(kt & 1) * 8192], &ldsB[(kt & 1) * 8192]);
            __syncthreads();   // drains prefetch (vmcnt 0) + syncs buffer reuse
        }
    } else {
        for (int kt = 0; kt < 16; ++kt) {
            __syncthreads();   // prior iter's ds_reads complete before overwrite
            stage(kt, 0);
            __syncthreads();   // vmcnt(0) drain: staged tile visible
            compute(ldsA, ldsB);
        }
    }
}

// ---------------------------------------------------------------------------
// Legacy GEMM core (register-staged, in-loop fp32->bf16): tier-B qkv only.
// ---------------------------------------------------------------------------
__device__ __forceinline__ void gemm_tile(const void* __restrict__ Ap,
                                          const bf16* __restrict__ Bp,
                                          int K, int m0, int n0,
                                          int af32, int aperm,
                                          bf16* ldsA, bf16* ldsB,
                                          f32x4 acc[4][4]) {
    const int tid = threadIdx.x, lane = tid & 63, wave = tid >> 6;
    const int l15 = lane & 15, q4 = lane >> 4;
    const int mw = (wave & 1) * 64, nw = (wave >> 1) * 64;

    #pragma unroll
    for (int i = 0; i < 4; i++)
        #pragma unroll
        for (int j = 0; j < 4; j++) {
            f32x4 z = {0.f, 0.f, 0.f, 0.f};
            acc[i][j] = z;
        }

    const int nkt = K / 64;
    for (int kt = 0; kt < nkt; ++kt) {
        __syncthreads();
        #pragma unroll
        for (int c0 = 0; c0 < 4; c0++) {
            int c = tid + c0 * 256;               // 1024 chunks of 8 elems
            int r = c >> 3, kc = (c & 7) << 3;
            size_t ae;
            if (aperm) {
                int m = m0 + r;
                ae = (((size_t)(m >> 11) * HH + kt) * NN + (m & (NN - 1))) * HD + kc;
            } else {
                ae = (size_t)(m0 + r) * K + kt * 64 + kc;
            }
            bf16x8 av;
            if (af32) {
                const f32x4* Af = (const f32x4*)((const float*)Ap + ae);
                f32x4 a0 = Af[0], a1 = Af[1];
                av[0] = (bf16)a0[0]; av[1] = (bf16)a0[1]; av[2] = (bf16)a0[2]; av[3] = (bf16)a0[3];
                av[4] = (bf16)a1[0]; av[5] = (bf16)a1[1]; av[6] = (bf16)a1[2]; av[7] = (bf16)a1[3];
            } else {
                av = *(const bf16x8*)((const bf16*)Ap + ae);
            }
            *(bf16x8*)&ldsA[r * 72 + kc] = av;
            size_t be = (size_t)(n0 + r) * K + kt * 64 + kc;
            *(bf16x8*)&ldsB[r * 72 + kc] = *(const bf16x8*)&Bp[be];
        }
        __syncthreads();
        #pragma unroll
        for (int ks = 0; ks < 2; ks++) {
            bf16x8 af[4], bfr[4];
            #pragma unroll
            for (int i = 0; i < 4; i++)
                af[i] = *(bf16x8*)&ldsA[(mw + i * 16 + l15) * 72 + ks * 32 + q4 * 8];
            #pragma unroll
            for (int j = 0; j < 4; j++)
                bfr[j] = *(bf16x8*)&ldsB[(nw + j * 16 + l15) * 72 + ks * 32 + q4 * 8];
            #pragma unroll
            for (int i = 0; i < 4; i++)
                #pragma unroll
                for (int j = 0; j < 4; j++)
                    acc[i][j] = MFMA16(af[i], bfr[j], acc[i][j]);
        }
    }
}

// ---------------------------------------------------------------------------
// Shared QKV epilogue. 'which' is block-uniform (n0 multiple of 128).
// V blocks pack 4 consecutive-m values into one b64 store.
// ---------------------------------------------------------------------------
__device__ __forceinline__ void qkv_epilogue(f32x4 acc[4][4], int m0, int n0,
                                             bf16* __restrict__ Qb,
                                             bf16* __restrict__ Kb,
                                             bf16* __restrict__ Vt) {
    const int tid = threadIdx.x, lane = tid & 63, wave = tid >> 6;
    const int l15 = lane & 15, q4 = lane >> 4;
    const int mw = (wave & 1) * 64, nw = (wave >> 1) * 64;

    if (n0 >= 2 * CC) {
        // V region: packed bf16x4 stores along nq
        #pragma unroll
        for (int i = 0; i < 4; i++) {
            #pragma unroll
            for (int j = 0; j < 4; j++) {
                int n = n0 - 2 * CC + nw + j * 16 + l15;   // 0..1023
                int h = n >> 6, d = n & 63;
                int mbase = m0 + mw + i * 16 + q4 * 4;     // 4 consecutive m, no 2048-cross
                int b = mbase >> 11, nq = mbase & (NN - 1);
                bf16x4 pv;
                #pragma unroll
                for (int r = 0; r < 4; r++) pv[r] = (bf16)acc[i][j][r];
                *(bf16x4*)&Vt[((size_t)(b * HH + h) * HD + d) * NN + nq] = pv;
            }
        }
    } else {
        const int isK = n0 >= CC;
        #pragma unroll
        for (int i = 0; i < 4; i++) {
            #pragma unroll
            for (int j = 0; j < 4; j++) {
                #pragma unroll
                for (int r = 0; r < 4; r++) {
                    int m = m0 + mw + i * 16 + q4 * 4 + r;
                    int n = (n0 & (CC - 1)) + nw + j * 16 + l15;
                    int h = n >> 6, d = n & 63;
                    int b = m >> 11, nq = m & (NN - 1);
                    size_t bh = (size_t)(b * HH + h);
                    float v = acc[i][j][r];
                    if (isK) Kb[(bh * NN + nq) * HD + d] = (bf16)v;
                    else     Qb[(bh * NN + nq) * HD + d] = (bf16)(v * QSCALE);
                }
            }
        }
    }
}

// ---------------------------------------------------------------------------
// Kernel 1a: QKV projection, fast path (A pre-converted to bf16).
// Single-buffer core (32KB LDS -> 3 blocks/CU implicit overlap).
// ---------------------------------------------------------------------------
__global__ __launch_bounds__(256, 2) void qkv_fast_kernel(const bf16* __restrict__ X16,
                                                          const bf16* __restrict__ Wqkv,
                                                          bf16* __restrict__ Qb,
                                                          bf16* __restrict__ Kb,
                                                          bf16* __restrict__ Vt) {
    __shared__ alignas(16) bf16 ldsA[128 * 64];
    __shared__ alignas(16) bf16 ldsB[128 * 64];
    f32x4 acc[4][4];
    const int m0 = blockIdx.y * 128, n0 = blockIdx.x * 128;
    gemm_tile_fast<0, 0>(X16, Wqkv, m0, n0, ldsA, ldsB, acc);
    qkv_epilogue(acc, m0, n0, Qb, Kb, Vt);
}

// ---------------------------------------------------------------------------
// Kernel 1b: QKV projection, legacy path (fp32/bf16 A, reg staging). Tier B.
// ---------------------------------------------------------------------------
__global__ __launch_bounds__(256, 2) void qkv_kernel(const void* __restrict__ X,
                                                     const bf16* __restrict__ Wqkv,
                                                     bf16* __restrict__ Qb,
                                                     bf16* __restrict__ Kb,
                                                     bf16* __restrict__ Vt) {
    __shared__ alignas(16) bf16 ldsA[128 * 72];
    __shared__ alignas(16) bf16 ldsB[128 * 72];
    const int f32 = detect_f32_block((const unsigned int*)X);
    f32x4 acc[4][4];
    const int m0 = blockIdx.y * 128, n0 = blockIdx.x * 128;
    gemm_tile(X, Wqkv, 1024, m0, n0, f32, 0, ldsA, ldsB, acc);
    qkv_epilogue(acc, m0, n0, Qb, Kb, Vt);
}

// ---------------------------------------------------------------------------
// Kernel 2: flash attention v12 (unchanged from R9/R11 measurement).
// ---------------------------------------------------------------------------
__global__ __launch_bounds__(256, 2) void attn_kernel(const bf16* __restrict__ Qb,
                                                      const bf16* __restrict__ Kb,
                                                      const bf16* __restrict__ Vt,
                                                      const unsigned long long* __restrict__ bm,
                                                      bf16* __restrict__ Ob) {
    __shared__ alignas(16) bf16 Kt[2][64 * 64];
    __shared__ alignas(16) bf16 Vs[2][64 * 64];    // [d][key], swizzled chunks
    __shared__ alignas(16) bf16 Ps[4][32 * 72];    // per-wave P tile (swizzled)

    // XCD swizzle: 512 blocks; XCD x gets logical blocks [x*64, x*64+64) = 4 bh
    const int wg = blockIdx.y * (NN / 128) + blockIdx.x;   // 512 blocks
    const int swzb = (wg & 7) * 64 + (wg >> 3);            // bijective (512%8==0)
    const int bh = swzb >> 4;
    const int qb = (swzb & 15) * 128;
    const int b = bh >> 4;
    const int tid = threadIdx.x, lane = tid & 63, wave = tid >> 6;
    const int l15 = lane & 15, q4 = lane >> 4;

    const bf16* Qp = Qb + (size_t)bh * NN * HD;
    const bf16* Kp = Kb + (size_t)bh * NN * HD;
    const bf16* Vp = Vt + (size_t)bh * HD * NN;

    // staging geometry: chunk g = wave*64 + lane + s2*256; row = g>>3,
    // logical chunk fetched = (g&7)^(row&7) (XOR swizzle on global source).
    const int srow0 = (wave * 64 + lane) >> 3;
    const int sc0 = ((wave * 64 + lane) & 7) ^ (srow0 & 7);
    const int srow1 = (wave * 64 + lane + 256) >> 3;
    const int sc1 = ((wave * 64 + lane + 256) & 7) ^ (srow1 & 7);

    // Q fragments for both 16-row halves: rows qrb + h*16 + l15
    const int qrb = qb + wave * 32;
    bf16x8 qf[2][2];
    #pragma unroll
    for (int h = 0; h < 2; h++)
        #pragma unroll
        for (int s = 0; s < 2; s++)
            qf[h][s] = *(const bf16x8*)&Qp[(size_t)(qrb + h * 16 + l15) * HD + s * 32 + q4 * 8];

    // ones B-fragment for the denominator MFMA
    bf16x8 ones;
    #pragma unroll
    for (int i = 0; i < 8; i++) ones[i] = (bf16)1.0f;

    const f32x4 FZ = {0.f, 0.f, 0.f, 0.f};

    f32x4 o[2][4];
    f32x4 lacc[2] = {FZ, FZ};
    #pragma unroll
    for (int h = 0; h < 2; h++)
        #pragma unroll
        for (int jd = 0; jd < 4; jd++) o[h][jd] = FZ;

    // bitmask: this lane's q-row word (S^T: one q per lane, l15) per half
    const unsigned long long* bmr = bm + ((size_t)b * NN + qrb + l15) * NW;

    bf16* Pw = &Ps[wave][0];
    const int swzP = (l15 >> 1) & 7;          // P block swizzle for this q-row
    const int pwrow = l15 * 72;               // P row base (elems), half adds 16*72

    // swizzled LDS read chunk offsets (elems) for K/V fragment loads
    const int rc0 = ((0 * 4 + q4) ^ (l15 & 7)) * 8;   // ks=0
    const int rc1 = ((1 * 4 + q4) ^ (l15 & 7)) * 8;   // ks=1

    // ---- helper lambdas (all static indexing after inlining) ----
    auto QK = [&](const bf16* KtC, f32x4 (&sj)[2][4]) {
        #pragma unroll
        for (int j = 0; j < 4; j++) {
            bf16x8 kf0 = *(const bf16x8*)&KtC[(j * 16 + l15) * 64 + rc0];
            sj[0][j] = MFMA16(kf0, qf[0][0], FZ);
            sj[1][j] = MFMA16(kf0, qf[1][0], FZ);
            bf16x8 kf1 = *(const bf16x8*)&KtC[(j * 16 + l15) * 64 + rc1];
            sj[0][j] = MFMA16(kf1, qf[0][1], sj[0][j]);
            sj[1][j] = MFMA16(kf1, qf[1][1], sj[1][j]);
        }
    };
    auto EXPSTORE = [&](f32x4 (&sj)[2][4], unsigned (&s0)[2], unsigned (&s1)[2]) {
        #pragma unroll
        for (int h = 0; h < 2; h++) {
            #pragma unroll
            for (int j = 0; j < 4; j++) {
                unsigned w = (j < 2) ? s0[h] : s1[h];
                unsigned ws = (j & 1) ? (w >> 16) : w;
                bf16x4 pv;
                #pragma unroll
                for (int r = 0; r < 4; r++) {
                    unsigned bit = (ws >> r) & 1u;
                    float ex = __builtin_amdgcn_exp2f(sj[h][j][r]);
                    pv[r] = (bf16)(bit ? ex : 0.f);
                }
                const int blk = (2 * j + (q4 >> 1)) ^ swzP;
                *(bf16x4*)&Pw[(h * 16 * 72) + pwrow + blk * 8 + (q4 & 1) * 4] = pv;
            }
        }
    };
    auto PV = [&](const bf16* VsC) {
        __builtin_amdgcn_s_setprio(1);
        #pragma unroll
        for (int ks = 0; ks < 2; ks++) {
            const int psw = ((4 * ks + q4) ^ swzP) * 8;
            bf16x8 pf0 = *(bf16x8*)&Pw[pwrow + psw];
            bf16x8 pf1 = *(bf16x8*)&Pw[(16 * 72) + pwrow + psw];
            lacc[0] = MFMA16(pf0, ones, lacc[0]);
            lacc[1] = MFMA16(pf1, ones, lacc[1]);
            const int rcv = (ks ? rc1 : rc0);
            #pragma unroll
            for (int jd = 0; jd < 4; jd++) {
                bf16x8 vf = *(const bf16x8*)&VsC[(jd * 16 + l15) * 64 + rcv];
                o[0][jd] = MFMA16(pf0, vf, o[0][jd]);
                o[1][jd] = MFMA16(pf1, vf, o[1][jd]);
            }
        }
        __builtin_amdgcn_s_setprio(0);
    };

    // ---- prologue: stage tile 0 (K and V), mask(0); then K1 + QK(0)
    async_cp16(&Kp[(size_t)srow0 * HD + sc0 * 8], &Kt[0][(wave * 64) * 8]);
    async_cp16(&Kp[(size_t)srow1 * HD + sc1 * 8], &Kt[0][(wave * 64 + 256) * 8]);
    async_cp16(&Vp[(size_t)srow0 * NN + sc0 * 8], &Vs[0][(wave * 64) * 8]);
    async_cp16(&Vp[(size_t)srow1 * NN + sc1 * 8], &Vs[0][(wave * 64 + 256) * 8]);
    unsigned long long mwreg[2];
    #pragma unroll
    for (int h = 0; h < 2; h++) mwreg[h] = bmr[(size_t)h * 16 * NW];
    __syncthreads();   // drain tile-0 loads

    // prefetch K tile 1 (slot 1 untouched so far)
    async_cp16(&Kp[(size_t)(64 + srow0) * HD + sc0 * 8], &Kt[1][(wave * 64) * 8]);
    async_cp16(&Kp[(size_t)(64 + srow1) * HD + sc1 * 8], &Kt[1][(wave * 64 + 256) * 8]);

    f32x4 sjA[2][4], sjB[2][4];
    unsigned mA0[2], mA1[2], mB0[2], mB1[2];

    QK(&Kt[0][0], sjA);                         // S for tile 0
    #pragma unroll
    for (int h = 0; h < 2; h++) {
        mA0[h] = ((unsigned)mwreg[h]) >> (q4 * 4);
        mA1[h] = ((unsigned)(mwreg[h] >> 32)) >> (q4 * 4);
        mwreg[h] = bmr[(size_t)h * 16 * NW + 1];
    }
    __syncthreads();   // drain K tile-1 loads (all waves' QK(0) reads done)

    // ---- skewed steady-state: STEP(kt) = QK(kt) || finish(kt-1)
    // Slot usage inside STEP(kt):  K write (kt+1)&1 | K read kt&1
    //                              V write kt&1     | V read (kt-1)&1   (disjoint)
    auto STEP = [&](int kt, f32x4 (&sjP)[2][4], f32x4 (&sjC)[2][4],
                    unsigned (&s0P)[2], unsigned (&s1P)[2],
                    unsigned (&s0N)[2], unsigned (&s1N)[2]) {
        const int ktn = (kt + 1) & (NN / 64 - 1);   // kt=31 wraps (garbage ok)
        // 1. K prefetch for kt+1 (slot (kt+1)&1; last readers ran in STEP(kt-1))
        {
            bf16* KtN = &Kt[(kt + 1) & 1][0];
            async_cp16(&Kp[(size_t)(ktn * 64 + srow0) * HD + sc0 * 8], &KtN[(wave * 64) * 8]);
            async_cp16(&Kp[(size_t)(ktn * 64 + srow1) * HD + sc1 * 8], &KtN[(wave * 64 + 256) * 8]);
        }
        // 2. V prefetch for THIS tile kt (slot kt&1; consumed by PV(kt) next
        //    STEP after this step's barrier; prior content V[kt-2] done in
        //    STEP(kt-1) behind its barrier; disjoint from PV's read slot).
        {
            bf16* VsN = &Vs[kt & 1][0];
            async_cp16(&Vp[(size_t)srow0 * NN + kt * 64 + sc0 * 8], &VsN[(wave * 64) * 8]);
            async_cp16(&Vp[(size_t)srow1 * NN + kt * 64 + sc1 * 8], &VsN[(wave * 64 + 256) * 8]);
        }
        // 3. QK(kt): MFMAs issue; results not consumed until next STEP
        QK(&Kt[kt & 1][0], sjC);
        // 4+5. finish tile kt-1 in the MFMA shadow: exp/mask -> P -> PV
        EXPSTORE(sjP, s0P, s1P);
        PV(&Vs[(kt - 1) & 1][0]);
        // 6. mask shifts for tile kt (consumed next STEP); prefetch mask kt+1
        #pragma unroll
        for (int h = 0; h < 2; h++) {
            s0N[h] = ((unsigned)mwreg[h]) >> (q4 * 4);
            s1N[h] = ((unsigned)(mwreg[h] >> 32)) >> (q4 * 4);
            mwreg[h] = bmr[(size_t)h * 16 * NW + ktn];
        }
        // 7. single barrier: drains K/V prefetch, syncs buffer reuse
        __syncthreads();
    };

    for (int kt = 1; kt <= 29; kt += 2) {
        STEP(kt,     sjA, sjB, mA0, mA1, mB0, mB1);
        STEP(kt + 1, sjB, sjA, mB0, mB1, mA0, mA1);
    }
    STEP(31, sjA, sjB, mA0, mA1, mB0, mB1);

    // ---- tail: finish tile 31 (V[31] staged in slot 1, drained at STEP(31))
    EXPSTORE(sjB, mB0, mB1);
    PV(&Vs[1][0]);

    // normalize + write (lacc[h][r] = rowsum for row h*16+q4*4+r)
    #pragma unroll
    for (int h = 0; h < 2; h++) {
        float rl[4];
        #pragma unroll
        for (int r = 0; r < 4; r++) rl[r] = 1.0f / lacc[h][r];
        #pragma unroll
        for (int jd = 0; jd < 4; jd++) {
            #pragma unroll
            for (int r = 0; r < 4; r++) {
                int q = qrb + h * 16 + q4 * 4 + r;
                int d = jd * 16 + l15;
                Ob[((size_t)bh * NN + q) * HD + d] = (bf16)(o[h][jd][r] * rl[r]);
            }
        }
    }
}

// ---------------------------------------------------------------------------
// Kernel 3: output projection + bias. DBUF=1 core (grid=256 = 1 block/CU).
// ---------------------------------------------------------------------------
__global__ __launch_bounds__(256, 2) void proj_fast_kernel(const bf16* __restrict__ Ain,
                                                           const bf16* __restrict__ Wp16,
                                                           const void* __restrict__ biasp,
                                                           void* __restrict__ Outd,
                                                           void* __restrict__ Tmp,
                                                           int direct) {
    __shared__ alignas(16) bf16 ldsA[2 * 128 * 64];
    __shared__ alignas(16) bf16 ldsB[2 * 128 * 64];
    const int f32 = detect_f32_block((const unsigned int*)biasp);
    f32x4 acc[4][4];
    const int m0 = blockIdx.y * 128, n0 = blockIdx.x * 128;
    gemm_tile_fast<1, 1>(Ain, Wp16, m0, n0, ldsA, ldsB, acc);

    const int tid = threadIdx.x, lane = tid & 63, wave = tid >> 6;
    const int l15 = lane & 15, q4 = lane >> 4;
    const int mw = (wave & 1) * 64, nw = (wave >> 1) * 64;
    #pragma unroll
    for (int i = 0; i < 4; i++) {
        #pragma unroll
        for (int j = 0; j < 4; j++) {
            #pragma unroll
            for (int r = 0; r < 4; r++) {
                int m = m0 + mw + i * 16 + q4 * 4 + r;
                int n = n0 + nw + j * 16 + l15;
                float bv = f32 ? ((const float*)biasp)[n] : (float)((const bf16*)biasp)[n];
                float val = acc[i][j][r] + bv;
                size_t idx = (size_t)m * CC + n;
                if (f32) {
                    if (direct || idx >= (size_t)2097152)   // byte off >= 8MB
                        ((float*)Outd)[idx] = val;
                    else
                        ((float*)Tmp)[idx] = val;
                } else {
                    if (direct) ((bf16*)Outd)[idx] = (bf16)val;
                    else        ((bf16*)Tmp)[idx] = (bf16)val;
                }
            }
        }
    }
}

// ---------------------------------------------------------------------------
// Memory map (fp32 output established => d_out = 16.78 MB):
//  d_out: [0, 8.39M)        Q scratch (tier B: attention O in-place)
//         [8.39M, 14.68M)   W_qkv bf16 (dead after qkv)
//         [14.68M, 15.73M)  key bitmask (dead after attn)
//  ws:    [0, 8.39M)        Kb (tier B: proj low-half staging after attn)
//         [8.39M, 16.78M)   Vt; (no-spare-ws: Wp16 here after attn)
//         tier A adds @16.78M: X16 bf16 (dead after qkv) then Ob (attn out)
//         spare-ws adds @25.17M: Wp16 bf16 (2 MB, written by prep)
// ---------------------------------------------------------------------------
extern "C" void kernel_launch(void* const* d_in, const int* in_sizes, int n_in,
                              void* d_out, int out_size, void* d_ws, size_t ws_size,
                              hipStream_t stream) {
    const void* x    = d_in[0];
    const void* mask = d_in[1];
    const void* Wqkv = d_in[2];
    const void* Wp   = d_in[3];
    const void* bias = d_in[4];

    char* ws = (char*)d_ws;
    const size_t QS  = (size_t)BB * HH * NN * HD;     // 4,194,304 elems
    const size_t QSB = QS * sizeof(bf16);             // 8,388,608 bytes
    const size_t WPB = (size_t)CC * CC * sizeof(bf16); // 2 MB
    bf16* Qb   = (bf16*)d_out;
    bf16* W16  = (bf16*)((char*)d_out + QSB);                      // 6.29 MB
    unsigned long long* bm = (unsigned long long*)((char*)d_out + QSB + 3 * CC * CC * 2);
    bf16* Kb   = (bf16*)ws;
    bf16* Vt   = (bf16*)(ws + QSB);

    if (ws_size >= 3 * QSB) {
        bf16* X16 = (bf16*)(ws + 2 * QSB);
        bf16* Ob  = (bf16*)(ws + 2 * QSB);   // reuses X16 slot (X16 dead after qkv)
        const int spareWp = (ws_size >= 3 * QSB + WPB);
        bf16* Wp16 = spareWp ? (bf16*)(ws + 3 * QSB) : (bf16*)(ws + QSB);

        if (spareWp) {
            // 4-launch path: Wp cvt folded into prep (region [5632,6144)).
            prep_kernel<<<6144, 256, 0, stream>>>(mask, bm, Wqkv, W16, x, X16, Wp, Wp16);
            qkv_fast_kernel<<<dim3(3072 / 128, 4096 / 128), 256, 0, stream>>>(X16, W16, Qb, Kb, Vt);
            attn_kernel<<<dim3(NN / 128, BB * HH), 256, 0, stream>>>(Qb, Kb, Vt, bm, Ob);
            proj_fast_kernel<<<dim3(1024 / 128, 4096 / 128), 256, 0, stream>>>(Ob, Wp16, bias, d_out, d_out, 1);
        } else {
            // fallback: Wp16 shares the Vt slot -> cvt must wait for attn.
            prep_kernel<<<5632, 256, 0, stream>>>(mask, bm, Wqkv, W16, x, X16, Wp, Wp16);
            qkv_fast_kernel<<<dim3(3072 / 128, 4096 / 128), 256, 0, stream>>>(X16, W16, Qb, Kb, Vt);
            attn_kernel<<<dim3(NN / 128, BB * HH), 256, 0, stream>>>(Qb, Kb, Vt, bm, Ob);
            cvt_bf16_kernel<<<CC * CC / (256 * 8), 256, 0, stream>>>(Wp, Wp16);
            proj_fast_kernel<<<dim3(1024 / 128, 4096 / 128), 256, 0, stream>>>(Ob, Wp16, bias, d_out, d_out, 1);
        }
    } else {
        bf16* Wp16 = (bf16*)(ws + QSB);                            // after attn (Vt dead)
        prep_kernel<<<3584, 256, 0, stream>>>(mask, bm, Wqkv, W16, x, (bf16*)ws, Wp, Wp16);
        qkv_kernel<<<dim3(3072 / 128, 4096 / 128), 256, 0, stream>>>(x, W16, Qb, Kb, Vt);
        attn_kernel<<<dim3(NN / 128, BB * HH), 256, 0, stream>>>(Qb, Kb, Vt, bm, Qb);
        cvt_bf16_kernel<<<CC * CC / (256 * 8), 256, 0, stream>>>(Wp, Wp16);
        proj_fast_kernel<<<dim3(1024 / 128, 4096 / 128), 256, 0, stream>>>(Qb, Wp16, bias, d_out, ws, 0);
        hipMemcpyAsync(d_out, ws, QSB, hipMemcpyDeviceToDevice, stream);
    }
}

// Round 13
// 253.371 us; speedup vs baseline: 1.0974x; 1.0035x over previous
//
#include <hip/hip_runtime.h>
#include <hip/hip_bf16.h>
#include <hip/hip_cooperative_groups.h>

namespace cg = cooperative_groups;

typedef __bf16 bf16;
typedef __bf16 bf16x4 __attribute__((ext_vector_type(4)));
typedef __bf16 bf16x8 __attribute__((ext_vector_type(8)));
typedef float f32x4 __attribute__((ext_vector_type(4)));

#define MFMA16(a, b, c) __builtin_amdgcn_mfma_f32_16x16x32_bf16((a), (b), (c), 0, 0, 0)

// Problem constants
#define BB 2
#define HH 16
#define NN 2048
#define CC 1024
#define HD 64
#define NW (NN / 64)   // 64-key words per row = 32

// Q pre-scale: HD^-0.5 * log2(e), so attention can use exp2 directly.
#define QSCALE 0.1803368867f

// ---------------------------------------------------------------------------
// Per-block dtype detectors (512-word scan, L2-hot, wave-uniform result).
// ---------------------------------------------------------------------------
__device__ __forceinline__ int detect_f32_block(const unsigned int* __restrict__ w) {
    __shared__ int bfc_s, tot_s;
    if (threadIdx.x == 0) { bfc_s = 0; tot_s = 0; }
    __syncthreads();
    int bfc = 0, tot = 0;
    for (int i = threadIdx.x; i < 512; i += blockDim.x) {
        unsigned v = w[i];
        if (v != 0u) {
            tot++;
            unsigned e = (v >> 7) & 0xFFu;
            if (e >= 100u && e <= 140u) bfc++;
        }
    }
    atomicAdd(&bfc_s, bfc); atomicAdd(&tot_s, tot);
    __syncthreads();
    int r = (2 * bfc_s < tot_s) ? 1 : 0;
    __syncthreads();
    return r;
}

// mask element size: int64 -> 8, int32/fp32 -> 4, int16/bf16 -> 2, byte -> 1
__device__ __forceinline__ int detect_esz_block(const unsigned int* __restrict__ w) {
    __shared__ int ok8s, ok4s, ok2s;
    if (threadIdx.x == 0) { ok8s = 1; ok4s = 1; ok2s = 1; }
    __syncthreads();
    int ok8 = 1, ok4 = 1, ok2 = 1;
    for (int i = threadIdx.x; i < 512; i += blockDim.x) {
        unsigned v = w[i];
        if ((i & 1) && v != 0u) ok8 = 0;
        if (!(v == 0u || v == 1u || v == 0x3F800000u)) ok4 = 0;
        unsigned lo = v & 0xFFFFu, hi = v >> 16;
        if (!((lo == 0u || lo == 1u || lo == 0x3F80u) &&
              (hi == 0u || hi == 1u || hi == 0x3F80u))) ok2 = 0;
    }
    if (!ok8) atomicAnd(&ok8s, 0);
    if (!ok4) atomicAnd(&ok4s, 0);
    if (!ok2) atomicAnd(&ok2s, 0);
    __syncthreads();
    int r = ok8s ? 8 : (ok4s ? 4 : (ok2s ? 2 : 1));
    __syncthreads();
    return r;
}

// 8-elem fp32->bf16 (or passthrough) convert
__device__ __forceinline__ void cvt8(const void* __restrict__ src, bf16* __restrict__ dst,
                                     size_t e, int f32) {
    bf16x8 v;
    if (f32) {
        const f32x4* S = (const f32x4*)((const float*)src + e);
        f32x4 a = S[0], b = S[1];
        v[0] = (bf16)a[0]; v[1] = (bf16)a[1]; v[2] = (bf16)a[2]; v[3] = (bf16)a[3];
        v[4] = (bf16)b[0]; v[5] = (bf16)b[1]; v[6] = (bf16)b[2]; v[7] = (bf16)b[3];
    } else {
        v = *(const bf16x8*)((const bf16*)src + e);
    }
    *(bf16x8*)&dst[e] = v;
}

// ---------------------------------------------------------------------------
// prep region worker: [0,2048) mask->bitmask; [2048,3584) Wqkv cvt;
// [3584,5632) X cvt; [5632,6144) Wp cvt.
// ---------------------------------------------------------------------------
__device__ __forceinline__ void prep_region(int bid,
                                            const void* maskp, unsigned long long* bm,
                                            const void* Wqkv, bf16* W16,
                                            const void* x, bf16* X16,
                                            const void* Wp, bf16* Wp16) {
    if (bid < 2048) {
        const int esz = detect_esz_block((const unsigned int*)maskp);  // wave-uniform
        const int lane = threadIdx.x & 63;
        const int wave = threadIdx.x >> 6;
        const long wbase = ((long)bid * 4 + wave) * 16;
        for (int i = 0; i < 16; i++) {
            long w = wbase + i;
            long idx = w * 64 + lane;
            bool mk;
            if (esz == 4)      mk = ((const unsigned int*)maskp)[idx] != 0u;
            else if (esz == 2) mk = ((const unsigned short*)maskp)[idx] != 0;
            else if (esz == 8) mk = ((const unsigned long long*)maskp)[idx] != 0ull;
            else               mk = ((const unsigned char*)maskp)[idx] != 0;
            unsigned long long b = __ballot(mk);
            if (lane == 0) bm[w] = b;
        }
    } else if (bid < 3584) {
        const int f32 = detect_f32_block((const unsigned int*)Wqkv);
        size_t e = ((size_t)(bid - 2048) * 256 + threadIdx.x) * 8;
        cvt8(Wqkv, W16, e, f32);
    } else if (bid < 5632) {
        const int f32 = detect_f32_block((const unsigned int*)x);
        size_t e = ((size_t)(bid - 3584) * 256 + threadIdx.x) * 8;
        cvt8(x, X16, e, f32);
    } else {
        const int f32 = detect_f32_block((const unsigned int*)Wp);
        size_t e = ((size_t)(bid - 5632) * 256 + threadIdx.x) * 8;
        cvt8(Wp, Wp16, e, f32);
    }
}

// ---------------------------------------------------------------------------
// Standalone prep kernel (fallback paths).
// ---------------------------------------------------------------------------
__global__ __launch_bounds__(256) void prep_kernel(const void* __restrict__ maskp,
                                                   unsigned long long* __restrict__ bm,
                                                   const void* __restrict__ Wqkv,
                                                   bf16* __restrict__ W16,
                                                   const void* __restrict__ x,
                                                   bf16* __restrict__ X16,
                                                   const void* __restrict__ Wp,
                                                   bf16* __restrict__ Wp16) {
    prep_region(blockIdx.x, maskp, bm, Wqkv, W16, x, X16, Wp, Wp16);
}

// ---------------------------------------------------------------------------
// Kernel: standalone convert (fallback: Wp after attn frees the Vt slot).
// ---------------------------------------------------------------------------
__global__ __launch_bounds__(256) void cvt_bf16_kernel(const void* __restrict__ src,
                                                       bf16* __restrict__ dst) {
    const int f32 = detect_f32_block((const unsigned int*)src);
    size_t e = ((size_t)blockIdx.x * 256 + threadIdx.x) * 8;
    cvt8(src, dst, e, f32);
}

// ---------------------------------------------------------------------------
// async 16B global -> LDS copy (direct-to-LDS, no VGPR round-trip).
// ---------------------------------------------------------------------------
__device__ __forceinline__ void async_cp16(const bf16* g, bf16* l) {
    __builtin_amdgcn_global_load_lds((const __attribute__((address_space(1))) void*)g,
                                     (__attribute__((address_space(3))) void*)l,
                                     16, 0, 0);
}

// ---------------------------------------------------------------------------
// Fast GEMM core: C[128x128] = A[128xK]*B[128xK]^T, K=1024.
// DBUF=0: single 32KB buffer, 2 barriers/iter (use when >=2 active blocks/CU
//   co-resident — implicit cross-block overlap hides latency; R10 lesson).
// DBUF=1: double buffer, 1 barrier/iter (use at 1 active block/CU).
// ---------------------------------------------------------------------------
template<int APERM, int DBUF>
__device__ __forceinline__ void gemm_tile_fast(const bf16* __restrict__ Ap,
                                               const bf16* __restrict__ Bp,
                                               int m0, int n0,
                                               bf16* ldsA, bf16* ldsB,
                                               f32x4 acc[4][4]) {
    const int K = 1024;
    const int tid = threadIdx.x, lane = tid & 63, wave = tid >> 6;
    const int l15 = lane & 15, q4 = lane >> 4;
    const int mw = (wave & 1) * 64, nw = (wave >> 1) * 64;

    #pragma unroll
    for (int i = 0; i < 4; i++)
        #pragma unroll
        for (int j = 0; j < 4; j++) {
            f32x4 z = {0.f, 0.f, 0.f, 0.f};
            acc[i][j] = z;
        }

    const int rA = tid >> 3;          // row within 32-row issue group
    const int colc = (tid & 7) << 3;  // col (elems) within 64-wide tile

    auto stage = [&](int kt, int buf) {
        #pragma unroll
        for (int i = 0; i < 4; i++) {
            int r = i * 32 + rA;
            size_t ae;
            if (APERM) {
                int m = m0 + r;
                ae = (((size_t)(m >> 11) * HH + kt) * NN + (m & (NN - 1))) * HD + colc;
            } else {
                ae = (size_t)(m0 + r) * K + kt * 64 + colc;
            }
            async_cp16(&Ap[ae], &ldsA[buf * 8192 + i * 2048 + wave * 512]);
            size_t be = (size_t)(n0 + r) * K + kt * 64 + colc;
            async_cp16(&Bp[be], &ldsB[buf * 8192 + i * 2048 + wave * 512]);
        }
    };

    auto compute = [&](const bf16* lA, const bf16* lB) {
        #pragma unroll
        for (int ks = 0; ks < 2; ks++) {
            bf16x8 af[4], bfr[4];
            #pragma unroll
            for (int i = 0; i < 4; i++)
                af[i] = *(const bf16x8*)&lA[(mw + i * 16 + l15) * 64 + ks * 32 + q4 * 8];
            #pragma unroll
            for (int j = 0; j < 4; j++)
                bfr[j] = *(const bf16x8*)&lB[(nw + j * 16 + l15) * 64 + ks * 32 + q4 * 8];
            #pragma unroll
            for (int i = 0; i < 4; i++)
                #pragma unroll
                for (int j = 0; j < 4; j++)
                    acc[i][j] = MFMA16(af[i], bfr[j], acc[i][j]);
        }
    };

    if (DBUF) {
        stage(0, 0);
        __syncthreads();   // drain tile 0
        for (int kt = 0; kt < 16; ++kt) {
            if (kt < 15) stage(kt + 1, (kt + 1) & 1);
            compute(&ldsA[(kt & 1) * 8192], &ldsB[(kt & 1) * 8192]);
            __syncthreads();   // drains prefetch (vmcnt 0) + syncs buffer reuse
        }
    } else {
        for (int kt = 0; kt < 16; ++kt) {
            __syncthreads();   // prior iter's ds_reads complete before overwrite
            stage(kt, 0);
            __syncthreads();   // vmcnt(0) drain: staged tile visible
            compute(ldsA, ldsB);
        }
    }
}

// ---------------------------------------------------------------------------
// Legacy GEMM core (register-staged, in-loop fp32->bf16): tier-B qkv only.
// ---------------------------------------------------------------------------
__device__ __forceinline__ void gemm_tile(const void* __restrict__ Ap,
                                          const bf16* __restrict__ Bp,
                                          int K, int m0, int n0,
                                          int af32, int aperm,
                                          bf16* ldsA, bf16* ldsB,
                                          f32x4 acc[4][4]) {
    const int tid = threadIdx.x, lane = tid & 63, wave = tid >> 6;
    const int l15 = lane & 15, q4 = lane >> 4;
    const int mw = (wave & 1) * 64, nw = (wave >> 1) * 64;

    #pragma unroll
    for (int i = 0; i < 4; i++)
        #pragma unroll
        for (int j = 0; j < 4; j++) {
            f32x4 z = {0.f, 0.f, 0.f, 0.f};
            acc[i][j] = z;
        }

    const int nkt = K / 64;
    for (int kt = 0; kt < nkt; ++kt) {
        __syncthreads();
        #pragma unroll
        for (int c0 = 0; c0 < 4; c0++) {
            int c = tid + c0 * 256;               // 1024 chunks of 8 elems
            int r = c >> 3, kc = (c & 7) << 3;
            size_t ae;
            if (aperm) {
                int m = m0 + r;
                ae = (((size_t)(m >> 11) * HH + kt) * NN + (m & (NN - 1))) * HD + kc;
            } else {
                ae = (size_t)(m0 + r) * K + kt * 64 + kc;
            }
            bf16x8 av;
            if (af32) {
                const f32x4* Af = (const f32x4*)((const float*)Ap + ae);
                f32x4 a0 = Af[0], a1 = Af[1];
                av[0] = (bf16)a0[0]; av[1] = (bf16)a0[1]; av[2] = (bf16)a0[2]; av[3] = (bf16)a0[3];
                av[4] = (bf16)a1[0]; av[5] = (bf16)a1[1]; av[6] = (bf16)a1[2]; av[7] = (bf16)a1[3];
            } else {
                av = *(const bf16x8*)((const bf16*)Ap + ae);
            }
            *(bf16x8*)&ldsA[r * 72 + kc] = av;
            size_t be = (size_t)(n0 + r) * K + kt * 64 + kc;
            *(bf16x8*)&ldsB[r * 72 + kc] = *(const bf16x8*)&Bp[be];
        }
        __syncthreads();
        #pragma unroll
        for (int ks = 0; ks < 2; ks++) {
            bf16x8 af[4], bfr[4];
            #pragma unroll
            for (int i = 0; i < 4; i++)
                af[i] = *(bf16x8*)&ldsA[(mw + i * 16 + l15) * 72 + ks * 32 + q4 * 8];
            #pragma unroll
            for (int j = 0; j < 4; j++)
                bfr[j] = *(bf16x8*)&ldsB[(nw + j * 16 + l15) * 72 + ks * 32 + q4 * 8];
            #pragma unroll
            for (int i = 0; i < 4; i++)
                #pragma unroll
                for (int j = 0; j < 4; j++)
                    acc[i][j] = MFMA16(af[i], bfr[j], acc[i][j]);
        }
    }
}

// ---------------------------------------------------------------------------
// Shared QKV epilogue. 'which' is block-uniform (n0 multiple of 128).
// ---------------------------------------------------------------------------
__device__ __forceinline__ void qkv_epilogue(f32x4 acc[4][4], int m0, int n0,
                                             bf16* __restrict__ Qb,
                                             bf16* __restrict__ Kb,
                                             bf16* __restrict__ Vt) {
    const int tid = threadIdx.x, lane = tid & 63, wave = tid >> 6;
    const int l15 = lane & 15, q4 = lane >> 4;
    const int mw = (wave & 1) * 64, nw = (wave >> 1) * 64;

    if (n0 >= 2 * CC) {
        // V region: packed bf16x4 stores along nq
        #pragma unroll
        for (int i = 0; i < 4; i++) {
            #pragma unroll
            for (int j = 0; j < 4; j++) {
                int n = n0 - 2 * CC + nw + j * 16 + l15;   // 0..1023
                int h = n >> 6, d = n & 63;
                int mbase = m0 + mw + i * 16 + q4 * 4;     // 4 consecutive m, no 2048-cross
                int b = mbase >> 11, nq = mbase & (NN - 1);
                bf16x4 pv;
                #pragma unroll
                for (int r = 0; r < 4; r++) pv[r] = (bf16)acc[i][j][r];
                *(bf16x4*)&Vt[((size_t)(b * HH + h) * HD + d) * NN + nq] = pv;
            }
        }
    } else {
        const int isK = n0 >= CC;
        #pragma unroll
        for (int i = 0; i < 4; i++) {
            #pragma unroll
            for (int j = 0; j < 4; j++) {
                #pragma unroll
                for (int r = 0; r < 4; r++) {
                    int m = m0 + mw + i * 16 + q4 * 4 + r;
                    int n = (n0 & (CC - 1)) + nw + j * 16 + l15;
                    int h = n >> 6, d = n & 63;
                    int b = m >> 11, nq = m & (NN - 1);
                    size_t bh = (size_t)(b * HH + h);
                    float v = acc[i][j][r];
                    if (isK) Kb[(bh * NN + nq) * HD + d] = (bf16)v;
                    else     Qb[(bh * NN + nq) * HD + d] = (bf16)(v * QSCALE);
                }
            }
        }
    }
}

// ---------------------------------------------------------------------------
// QKV phase worker (single-buffer core; caller provides 32KB of LDS).
// ---------------------------------------------------------------------------
__device__ __forceinline__ void qkv_phase(int wg, bf16* ldsA, bf16* ldsB,
                                          const bf16* X16, const bf16* W16,
                                          bf16* Qb, bf16* Kb, bf16* Vt) {
    f32x4 acc[4][4];
    const int m0 = (wg / 24) * 128, n0 = (wg % 24) * 128;
    gemm_tile_fast<0, 0>(X16, W16, m0, n0, ldsA, ldsB, acc);
    qkv_epilogue(acc, m0, n0, Qb, Kb, Vt);
}

// ---------------------------------------------------------------------------
// Kernel 1a: QKV projection, fast path (standalone fallback).
// ---------------------------------------------------------------------------
__global__ __launch_bounds__(256, 2) void qkv_fast_kernel(const bf16* __restrict__ X16,
                                                          const bf16* __restrict__ Wqkv,
                                                          bf16* __restrict__ Qb,
                                                          bf16* __restrict__ Kb,
                                                          bf16* __restrict__ Vt) {
    __shared__ alignas(16) bf16 ldsA[128 * 64];
    __shared__ alignas(16) bf16 ldsB[128 * 64];
    qkv_phase(blockIdx.y * 24 + blockIdx.x, ldsA, ldsB, X16, Wqkv, Qb, Kb, Vt);
}

// ---------------------------------------------------------------------------
// Kernel 1b: QKV projection, legacy path (fp32/bf16 A, reg staging). Tier B.
// ---------------------------------------------------------------------------
__global__ __launch_bounds__(256, 2) void qkv_kernel(const void* __restrict__ X,
                                                     const bf16* __restrict__ Wqkv,
                                                     bf16* __restrict__ Qb,
                                                     bf16* __restrict__ Kb,
                                                     bf16* __restrict__ Vt) {
    __shared__ alignas(16) bf16 ldsA[128 * 72];
    __shared__ alignas(16) bf16 ldsB[128 * 72];
    const int f32 = detect_f32_block((const unsigned int*)X);
    f32x4 acc[4][4];
    const int m0 = blockIdx.y * 128, n0 = blockIdx.x * 128;
    gemm_tile(X, Wqkv, 1024, m0, n0, f32, 0, ldsA, ldsB, acc);
    qkv_epilogue(acc, m0, n0, Qb, Kb, Vt);
}

// ---------------------------------------------------------------------------
// Flash attention phase (v12, race-fixed 1-tile skew). smemc: 51200 bytes.
// Layout (elems): Kt slots @0,4096; Vs slots @8192,12288; Ps @16384+wave*2304.
// ---------------------------------------------------------------------------
__device__ __forceinline__ void attn_phase(const int wg, char* smemc,
                                           const bf16* Qb, const bf16* Kb,
                                           const bf16* Vt,
                                           const unsigned long long* bm,
                                           bf16* Ob) {
    bf16* KtB = (bf16*)smemc;
    bf16* VsB = (bf16*)smemc + 8192;
    bf16* PsB = (bf16*)smemc + 16384;

    // XCD swizzle over 512 logical blocks
    const int swzb = (wg & 7) * 64 + (wg >> 3);            // bijective (512%8==0)
    const int bh = swzb >> 4;
    const int qb = (swzb & 15) * 128;
    const int b = bh >> 4;
    const int tid = threadIdx.x, lane = tid & 63, wave = tid >> 6;
    const int l15 = lane & 15, q4 = lane >> 4;

    const bf16* Qp = Qb + (size_t)bh * NN * HD;
    const bf16* Kp = Kb + (size_t)bh * NN * HD;
    const bf16* Vp = Vt + (size_t)bh * HD * NN;

    // staging geometry: chunk g = wave*64 + lane + s2*256; row = g>>3,
    // logical chunk fetched = (g&7)^(row&7) (XOR swizzle on global source).
    const int srow0 = (wave * 64 + lane) >> 3;
    const int sc0 = ((wave * 64 + lane) & 7) ^ (srow0 & 7);
    const int srow1 = (wave * 64 + lane + 256) >> 3;
    const int sc1 = ((wave * 64 + lane + 256) & 7) ^ (srow1 & 7);

    // Q fragments for both 16-row halves: rows qrb + h*16 + l15
    const int qrb = qb + wave * 32;
    bf16x8 qf[2][2];
    #pragma unroll
    for (int h = 0; h < 2; h++)
        #pragma unroll
        for (int s = 0; s < 2; s++)
            qf[h][s] = *(const bf16x8*)&Qp[(size_t)(qrb + h * 16 + l15) * HD + s * 32 + q4 * 8];

    bf16x8 ones;
    #pragma unroll
    for (int i = 0; i < 8; i++) ones[i] = (bf16)1.0f;

    const f32x4 FZ = {0.f, 0.f, 0.f, 0.f};

    f32x4 o[2][4];
    f32x4 lacc[2] = {FZ, FZ};
    #pragma unroll
    for (int h = 0; h < 2; h++)
        #pragma unroll
        for (int jd = 0; jd < 4; jd++) o[h][jd] = FZ;

    const unsigned long long* bmr = bm + ((size_t)b * NN + qrb + l15) * NW;

    bf16* Pw = PsB + wave * (32 * 72);
    const int swzP = (l15 >> 1) & 7;          // P block swizzle for this q-row
    const int pwrow = l15 * 72;               // P row base (elems), half adds 16*72

    const int rc0 = ((0 * 4 + q4) ^ (l15 & 7)) * 8;   // ks=0
    const int rc1 = ((1 * 4 + q4) ^ (l15 & 7)) * 8;   // ks=1

    auto QK = [&](const bf16* KtC, f32x4 (&sj)[2][4]) {
        #pragma unroll
        for (int j = 0; j < 4; j++) {
            bf16x8 kf0 = *(const bf16x8*)&KtC[(j * 16 + l15) * 64 + rc0];
            sj[0][j] = MFMA16(kf0, qf[0][0], FZ);
            sj[1][j] = MFMA16(kf0, qf[1][0], FZ);
            bf16x8 kf1 = *(const bf16x8*)&KtC[(j * 16 + l15) * 64 + rc1];
            sj[0][j] = MFMA16(kf1, qf[0][1], sj[0][j]);
            sj[1][j] = MFMA16(kf1, qf[1][1], sj[1][j]);
        }
    };
    auto EXPSTORE = [&](f32x4 (&sj)[2][4], unsigned (&s0)[2], unsigned (&s1)[2]) {
        #pragma unroll
        for (int h = 0; h < 2; h++) {
            #pragma unroll
            for (int j = 0; j < 4; j++) {
                unsigned w = (j < 2) ? s0[h] : s1[h];
                unsigned ws = (j & 1) ? (w >> 16) : w;
                bf16x4 pv;
                #pragma unroll
                for (int r = 0; r < 4; r++) {
                    unsigned bit = (ws >> r) & 1u;
                    float ex = __builtin_amdgcn_exp2f(sj[h][j][r]);
                    pv[r] = (bf16)(bit ? ex : 0.f);
                }
                const int blk = (2 * j + (q4 >> 1)) ^ swzP;
                *(bf16x4*)&Pw[(h * 16 * 72) + pwrow + blk * 8 + (q4 & 1) * 4] = pv;
            }
        }
    };
    auto PV = [&](const bf16* VsC) {
        __builtin_amdgcn_s_setprio(1);
        #pragma unroll
        for (int ks = 0; ks < 2; ks++) {
            const int psw = ((4 * ks + q4) ^ swzP) * 8;
            bf16x8 pf0 = *(bf16x8*)&Pw[pwrow + psw];
            bf16x8 pf1 = *(bf16x8*)&Pw[(16 * 72) + pwrow + psw];
            lacc[0] = MFMA16(pf0, ones, lacc[0]);
            lacc[1] = MFMA16(pf1, ones, lacc[1]);
            const int rcv = (ks ? rc1 : rc0);
            #pragma unroll
            for (int jd = 0; jd < 4; jd++) {
                bf16x8 vf = *(const bf16x8*)&VsC[(jd * 16 + l15) * 64 + rcv];
                o[0][jd] = MFMA16(pf0, vf, o[0][jd]);
                o[1][jd] = MFMA16(pf1, vf, o[1][jd]);
            }
        }
        __builtin_amdgcn_s_setprio(0);
    };

    // ---- prologue: stage tile 0 (K and V), mask(0); then K1 + QK(0)
    async_cp16(&Kp[(size_t)srow0 * HD + sc0 * 8], &KtB[wave * 512]);
    async_cp16(&Kp[(size_t)srow1 * HD + sc1 * 8], &KtB[wave * 512 + 2048]);
    async_cp16(&Vp[(size_t)srow0 * NN + sc0 * 8], &VsB[wave * 512]);
    async_cp16(&Vp[(size_t)srow1 * NN + sc1 * 8], &VsB[wave * 512 + 2048]);
    unsigned long long mwreg[2];
    #pragma unroll
    for (int h = 0; h < 2; h++) mwreg[h] = bmr[(size_t)h * 16 * NW];
    __syncthreads();   // drain tile-0 loads

    // prefetch K tile 1 (slot 1 untouched so far)
    async_cp16(&Kp[(size_t)(64 + srow0) * HD + sc0 * 8], &KtB[4096 + wave * 512]);
    async_cp16(&Kp[(size_t)(64 + srow1) * HD + sc1 * 8], &KtB[4096 + wave * 512 + 2048]);

    f32x4 sjA[2][4], sjB[2][4];
    unsigned mA0[2], mA1[2], mB0[2], mB1[2];

    QK(KtB, sjA);                               // S for tile 0
    #pragma unroll
    for (int h = 0; h < 2; h++) {
        mA0[h] = ((unsigned)mwreg[h]) >> (q4 * 4);
        mA1[h] = ((unsigned)(mwreg[h] >> 32)) >> (q4 * 4);
        mwreg[h] = bmr[(size_t)h * 16 * NW + 1];
    }
    __syncthreads();   // drain K tile-1 loads (all waves' QK(0) reads done)

    // ---- skewed steady-state: STEP(kt) = QK(kt) || finish(kt-1)
    // Slot usage inside STEP(kt):  K write (kt+1)&1 | K read kt&1
    //                              V write kt&1     | V read (kt-1)&1  (disjoint)
    auto STEP = [&](int kt, f32x4 (&sjP)[2][4], f32x4 (&sjC)[2][4],
                    unsigned (&s0P)[2], unsigned (&s1P)[2],
                    unsigned (&s0N)[2], unsigned (&s1N)[2]) {
        const int ktn = (kt + 1) & (NN / 64 - 1);   // kt=31 wraps (garbage ok)
        {
            bf16* KtN = KtB + ((kt + 1) & 1) * 4096;
            async_cp16(&Kp[(size_t)(ktn * 64 + srow0) * HD + sc0 * 8], &KtN[wave * 512]);
            async_cp16(&Kp[(size_t)(ktn * 64 + srow1) * HD + sc1 * 8], &KtN[wave * 512 + 2048]);
        }
        {
            bf16* VsN = VsB + (kt & 1) * 4096;
            async_cp16(&Vp[(size_t)srow0 * NN + kt * 64 + sc0 * 8], &VsN[wave * 512]);
            async_cp16(&Vp[(size_t)srow1 * NN + kt * 64 + sc1 * 8], &VsN[wave * 512 + 2048]);
        }
        QK(KtB + (kt & 1) * 4096, sjC);
        EXPSTORE(sjP, s0P, s1P);
        PV(VsB + ((kt - 1) & 1) * 4096);
        #pragma unroll
        for (int h = 0; h < 2; h++) {
            s0N[h] = ((unsigned)mwreg[h]) >> (q4 * 4);
            s1N[h] = ((unsigned)(mwreg[h] >> 32)) >> (q4 * 4);
            mwreg[h] = bmr[(size_t)h * 16 * NW + ktn];
        }
        __syncthreads();
    };

    for (int kt = 1; kt <= 29; kt += 2) {
        STEP(kt,     sjA, sjB, mA0, mA1, mB0, mB1);
        STEP(kt + 1, sjB, sjA, mB0, mB1, mA0, mA1);
    }
    STEP(31, sjA, sjB, mA0, mA1, mB0, mB1);

    // ---- tail: finish tile 31 (V[31] staged in slot 1, drained at STEP(31))
    EXPSTORE(sjB, mB0, mB1);
    PV(VsB + 4096);

    // normalize + write (lacc[h][r] = rowsum for row h*16+q4*4+r)
    #pragma unroll
    for (int h = 0; h < 2; h++) {
        float rl[4];
        #pragma unroll
        for (int r = 0; r < 4; r++) rl[r] = 1.0f / lacc[h][r];
        #pragma unroll
        for (int jd = 0; jd < 4; jd++) {
            #pragma unroll
            for (int r = 0; r < 4; r++) {
                int q = qrb + h * 16 + q4 * 4 + r;
                int d = jd * 16 + l15;
                Ob[((size_t)bh * NN + q) * HD + d] = (bf16)(o[h][jd][r] * rl[r]);
            }
        }
    }
}

// ---------------------------------------------------------------------------
// Kernel 2: flash attention (standalone fallback).
// ---------------------------------------------------------------------------
__global__ __launch_bounds__(256, 2) void attn_kernel(const bf16* __restrict__ Qb,
                                                      const bf16* __restrict__ Kb,
                                                      const bf16* __restrict__ Vt,
                                                      const unsigned long long* __restrict__ bm,
                                                      bf16* __restrict__ Ob) {
    __shared__ alignas(16) char smem[51200];
    attn_phase(blockIdx.y * (NN / 128) + blockIdx.x, smem, Qb, Kb, Vt, bm, Ob);
}

// ---------------------------------------------------------------------------
// Proj phase worker (single-buffer core; direct store). 32KB LDS.
// ---------------------------------------------------------------------------
__device__ __forceinline__ void proj_phase(int id, bf16* ldsA, bf16* ldsB,
                                           const bf16* Ain, const bf16* Wp16,
                                           const void* biasp, void* Outd) {
    const int f32 = detect_f32_block((const unsigned int*)biasp);
    f32x4 acc[4][4];
    const int m0 = (id / 8) * 128, n0 = (id % 8) * 128;
    gemm_tile_fast<1, 0>(Ain, Wp16, m0, n0, ldsA, ldsB, acc);

    const int tid = threadIdx.x, lane = tid & 63, wave = tid >> 6;
    const int l15 = lane & 15, q4 = lane >> 4;
    const int mw = (wave & 1) * 64, nw = (wave >> 1) * 64;
    #pragma unroll
    for (int i = 0; i < 4; i++) {
        #pragma unroll
        for (int j = 0; j < 4; j++) {
            #pragma unroll
            for (int r = 0; r < 4; r++) {
                int m = m0 + mw + i * 16 + q4 * 4 + r;
                int n = n0 + nw + j * 16 + l15;
                float bv = f32 ? ((const float*)biasp)[n] : (float)((const bf16*)biasp)[n];
                float val = acc[i][j][r] + bv;
                size_t idx = (size_t)m * CC + n;
                if (f32) ((float*)Outd)[idx] = val;
                else     ((bf16*)Outd)[idx] = (bf16)val;
            }
        }
    }
}

// ---------------------------------------------------------------------------
// Kernel 3: output projection + bias (standalone, dbuf; fallback paths).
// ---------------------------------------------------------------------------
__global__ __launch_bounds__(256, 2) void proj_fast_kernel(const bf16* __restrict__ Ain,
                                                           const bf16* __restrict__ Wp16,
                                                           const void* __restrict__ biasp,
                                                           void* __restrict__ Outd,
                                                           void* __restrict__ Tmp,
                                                           int direct) {
    __shared__ alignas(16) bf16 ldsA[2 * 128 * 64];
    __shared__ alignas(16) bf16 ldsB[2 * 128 * 64];
    const int f32 = detect_f32_block((const unsigned int*)biasp);
    f32x4 acc[4][4];
    const int m0 = blockIdx.y * 128, n0 = blockIdx.x * 128;
    gemm_tile_fast<1, 1>(Ain, Wp16, m0, n0, ldsA, ldsB, acc);

    const int tid = threadIdx.x, lane = tid & 63, wave = tid >> 6;
    const int l15 = lane & 15, q4 = lane >> 4;
    const int mw = (wave & 1) * 64, nw = (wave >> 1) * 64;
    #pragma unroll
    for (int i = 0; i < 4; i++) {
        #pragma unroll
        for (int j = 0; j < 4; j++) {
            #pragma unroll
            for (int r = 0; r < 4; r++) {
                int m = m0 + mw + i * 16 + q4 * 4 + r;
                int n = n0 + nw + j * 16 + l15;
                float bv = f32 ? ((const float*)biasp)[n] : (float)((const bf16*)biasp)[n];
                float val = acc[i][j][r] + bv;
                size_t idx = (size_t)m * CC + n;
                if (f32) {
                    if (direct || idx >= (size_t)2097152)   // byte off >= 8MB
                        ((float*)Outd)[idx] = val;
                    else
                        ((float*)Tmp)[idx] = val;
                } else {
                    if (direct) ((bf16*)Outd)[idx] = (bf16)val;
                    else        ((bf16*)Tmp)[idx] = (bf16)val;
                }
            }
        }
    }
}

// ---------------------------------------------------------------------------
// Fused cooperative mega-kernel: prep -> qkv -> attn -> proj with grid.sync.
// Grid = 768 blocks x 256 thr = exactly 3 blocks/CU (LDS 51200x3 <= 160KB).
// Phase activity chosen so active blocks are balanced per CU under either
// packed or round-robin block->CU assignment:
//   qkv: all 768 (1 tile each); attn: wg%3!=2 (2 of every 3 -> 512 ids);
//   proj: wg%3==0 (1 of every 3 -> 256 ids).
// ---------------------------------------------------------------------------
__global__ __launch_bounds__(256, 3) void fused_all(
        const void* maskp, unsigned long long* bm,
        const void* Wqkv, bf16* W16,
        const void* x, bf16* X16,
        const void* Wp, bf16* Wp16,
        bf16* Qb, bf16* Kb, bf16* Vt,
        bf16* Ob, const void* biasp, void* Outd) {
    __shared__ alignas(16) char smem[51200];
    cg::grid_group grid = cg::this_grid();
    const int wg = blockIdx.x;

    // Phase 0: prep (grid-stride over 6144 regions)
    #pragma unroll 1
    for (int i = 0; i < 8; i++)
        prep_region(wg + i * 768, maskp, bm, Wqkv, W16, x, X16, Wp, Wp16);
    grid.sync();

    // Phase 1: qkv (768 tiles, 1:1)
    qkv_phase(wg, (bf16*)smem, (bf16*)(smem + 16384), X16, W16, Qb, Kb, Vt);
    grid.sync();

    // Phase 2: attention (512 logical blocks; 2 active per 3-block CU group)
    if (wg % 3 != 2)
        attn_phase((wg / 3) * 2 + (wg % 3), smem, Qb, Kb, Vt, bm, Ob);
    grid.sync();

    // Phase 3: proj (256 logical blocks; 1 active per 3-block CU group)
    if (wg % 3 == 0)
        proj_phase(wg / 3, (bf16*)smem, (bf16*)(smem + 16384), Ob, Wp16, biasp, Outd);
}

// ---------------------------------------------------------------------------
// Memory map (fp32 output established => d_out = 16.78 MB):
//  d_out: [0, 8.39M)        Q scratch
//         [8.39M, 14.68M)   W_qkv bf16 (dead after qkv)
//         [14.68M, 15.73M)  key bitmask (dead after attn)
//  ws:    [0, 8.39M)        Kb
//         [8.39M, 16.78M)   Vt
//         [16.78M, 25.17M)  X16 (dead after qkv) then Ob (attn out)
//         [25.17M, 27.27M)  Wp16 (spare-ws tier)
// ---------------------------------------------------------------------------
extern "C" void kernel_launch(void* const* d_in, const int* in_sizes, int n_in,
                              void* d_out, int out_size, void* d_ws, size_t ws_size,
                              hipStream_t stream) {
    const void* x    = d_in[0];
    const void* mask = d_in[1];
    const void* Wqkv = d_in[2];
    const void* Wp   = d_in[3];
    const void* bias = d_in[4];

    char* ws = (char*)d_ws;
    const size_t QS  = (size_t)BB * HH * NN * HD;      // 4,194,304 elems
    const size_t QSB = QS * sizeof(bf16);              // 8,388,608 bytes
    const size_t WPB = (size_t)CC * CC * sizeof(bf16); // 2 MB
    bf16* Qb   = (bf16*)d_out;
    bf16* W16  = (bf16*)((char*)d_out + QSB);                      // 6.29 MB
    unsigned long long* bm = (unsigned long long*)((char*)d_out + QSB + 3 * CC * CC * 2);
    bf16* Kb   = (bf16*)ws;
    bf16* Vt   = (bf16*)(ws + QSB);

    if (ws_size >= 3 * QSB) {
        bf16* X16 = (bf16*)(ws + 2 * QSB);
        bf16* Ob  = (bf16*)(ws + 2 * QSB);   // reuses X16 slot (X16 dead after qkv)
        const int spareWp = (ws_size >= 3 * QSB + WPB);
        bf16* Wp16 = spareWp ? (bf16*)(ws + 3 * QSB) : (bf16*)(ws + QSB);

        int coopOk = 0;
        if (spareWp) {
            int maxb = 0;
            if (hipOccupancyMaxActiveBlocksPerMultiprocessor(&maxb, fused_all, 256, 0)
                    == hipSuccess && maxb >= 3)
                coopOk = 1;
        }

        if (coopOk) {
            // Single cooperative launch: prep -> qkv -> attn -> proj.
            void* outv = d_out;
            void* kargs[] = {
                (void*)&mask, (void*)&bm, (void*)&Wqkv, (void*)&W16,
                (void*)&x, (void*)&X16, (void*)&Wp, (void*)&Wp16,
                (void*)&Qb, (void*)&Kb, (void*)&Vt, (void*)&Ob,
                (void*)&bias, (void*)&outv
            };
            hipLaunchCooperativeKernel(fused_all, dim3(768), dim3(256),
                                       kargs, 0, stream);
        } else if (spareWp) {
            // R12 4-launch path.
            prep_kernel<<<6144, 256, 0, stream>>>(mask, bm, Wqkv, W16, x, X16, Wp, Wp16);
            qkv_fast_kernel<<<dim3(3072 / 128, 4096 / 128), 256, 0, stream>>>(X16, W16, Qb, Kb, Vt);
            attn_kernel<<<dim3(NN / 128, BB * HH), 256, 0, stream>>>(Qb, Kb, Vt, bm, Ob);
            proj_fast_kernel<<<dim3(1024 / 128, 4096 / 128), 256, 0, stream>>>(Ob, Wp16, bias, d_out, d_out, 1);
        } else {
            // fallback: Wp16 shares the Vt slot -> cvt must wait for attn.
            prep_kernel<<<5632, 256, 0, stream>>>(mask, bm, Wqkv, W16, x, X16, Wp, Wp16);
            qkv_fast_kernel<<<dim3(3072 / 128, 4096 / 128), 256, 0, stream>>>(X16, W16, Qb, Kb, Vt);
            attn_kernel<<<dim3(NN / 128, BB * HH), 256, 0, stream>>>(Qb, Kb, Vt, bm, Ob);
            cvt_bf16_kernel<<<CC * CC / (256 * 8), 256, 0, stream>>>(Wp, Wp16);
            proj_fast_kernel<<<dim3(1024 / 128, 4096 / 128), 256, 0, stream>>>(Ob, Wp16, bias, d_out, d_out, 1);
        }
    } else {
        bf16* Wp16 = (bf16*)(ws + QSB);                            // after attn (Vt dead)
        prep_kernel<<<3584, 256, 0, stream>>>(mask, bm, Wqkv, W16, x, (bf16*)ws, Wp, Wp16);
        qkv_kernel<<<dim3(3072 / 128, 4096 / 128), 256, 0, stream>>>(x, W16, Qb, Kb, Vt);
        attn_kernel<<<dim3(NN / 128, BB * HH), 256, 0, stream>>>(Qb, Kb, Vt, bm, Qb);
        cvt_bf16_kernel<<<CC * CC / (256 * 8), 256, 0, stream>>>(Wp, Wp16);
        proj_fast_kernel<<<dim3(1024 / 128, 4096 / 128), 256, 0, stream>>>(Qb, Wp16, bias, d_out, ws, 0);
        hipMemcpyAsync(d_out, ws, QSB, hipMemcpyDeviceToDevice, stream);
    }
}